// Round 16
// baseline (9029.704 us; speedup 1.0000x reference)
//
#include <hip/hip_runtime.h>
#include <math.h>

// Dims: B=128, T=256, D=512, F0=2048, F1=1024, R=B*T=32768
//
// ws layout (BYTE offsets):
//  e0hi @ 0, e0lo @ 33554432, e1hi @ 67108864, e1lo @ 100663296
//  H0int @ 134217728 (67371008 B: 257 slots x 65536 u32, (hi<<16)|lo)
//  H1int @ 201588736 (67371008 B)
//  bar  @ 269484032  flags[4][64][16] + gen[4][32][16] ints (pre-scan region)
//  psum @ 269484032, psq @ 269746176, mean @ 270008320, scl @ 270010368
//  bc0 @ 270012416, bc1 @ 270020608
//  wr0hi@ 270028800, wr0lo@ 274223104, wr1hi@ 278417408, wr1lo@ 282611712
//  we0hi@ 286806016, we0lo@ 288903168, we1hi@ 291000320, we1lo@ 292048896
//  wg0hi@ 293097472 .. wf2lo@ 296767488
//  Y temp (fp32 64MB) aliases H0int (pre-scan only).
//
// r16 = r15 + ONE variable: h publish via LDS-staged COALESCED stores.
// A block's 512 h-values occupy exactly two contiguous 1KB global chunks
// (ksub=s>>1, (d>>3)&1=s&1 are block-constant). Epilogue writes a 2KB LDS
// tile; after a matched extra __syncthreads, all 4 waves store it with 256
// coalesced 8B device-scope stores (32 cache lines) instead of 512 scattered
// 4B atomics. sig target 4/step (all waves drain).

typedef short s16x8 __attribute__((ext_vector_type(8)));
typedef float f32x4 __attribute__((ext_vector_type(4)));
typedef float f32x16 __attribute__((ext_vector_type(16)));
typedef unsigned short u16;
typedef unsigned long long u64;

__device__ __forceinline__ float sigmoidf_(float x){ return 1.0f/(1.0f+expf(-x)); }

__device__ __forceinline__ u16 f2bf(float x){
  unsigned int u = __float_as_uint(x);
  unsigned int r = u + 0x7fffu + ((u>>16)&1u);
  return (u16)(r>>16);
}
__device__ __forceinline__ float bf2f(u16 s){ return __uint_as_float(((unsigned int)s)<<16); }

// unpack 8 interleaved u32 ((hi<<16)|lo) -> two s16x8 fragments
__device__ __forceinline__ void unpack8(const unsigned int* __restrict__ p,
                                        s16x8& hi, s16x8& lo){
  uint4 w0 = *(const uint4*)p;
  uint4 w1 = *(const uint4*)(p+4);
  union { unsigned int u[4]; s16x8 v; } H, L;
  H.u[0] = (w0.x>>16) | (w0.y & 0xffff0000u);
  H.u[1] = (w0.z>>16) | (w0.w & 0xffff0000u);
  H.u[2] = (w1.x>>16) | (w1.y & 0xffff0000u);
  H.u[3] = (w1.z>>16) | (w1.w & 0xffff0000u);
  L.u[0] = (w0.x & 0xffffu) | (w0.y<<16);
  L.u[1] = (w0.z & 0xffffu) | (w0.w<<16);
  L.u[2] = (w1.x & 0xffffu) | (w1.y<<16);
  L.u[3] = (w1.z & 0xffffu) | (w1.w<<16);
  hi = H.v; lo = L.v;
}

// ============ weight prep ====================================================
__global__ __launch_bounds__(256) void split_plain(const float* __restrict__ src,
                                                   u16* __restrict__ hi, u16* __restrict__ lo, int n)
{
  int i = blockIdx.x*256 + threadIdx.x;
  if (i < n){
    float v = src[i];
    u16 h = f2bf(v);
    hi[i] = h;
    lo[i] = f2bf(v - bf2f(h));
  }
}

__global__ __launch_bounds__(256) void split_fragW(const float* __restrict__ src,
                                                   u16* __restrict__ hi, u16* __restrict__ lo,
                                                   int N, int K)
{
  int i = blockIdx.x*256 + threadIdx.x;
  if (i >= N*K) return;
  int n = i / K, k = i - n*K;
  float v = src[i];
  u16 h = f2bf(v), l2 = f2bf(v - bf2f(h));
  size_t off = ((((size_t)(k>>4)*(N/32) + (n>>5))*64) + ((k>>3)&1)*32 + (n&31))*8 + (k&7);
  hi[off] = h; lo[off] = l2;
}

__global__ __launch_bounds__(256) void split_gates2(const float* __restrict__ wih,
                                                    const float* __restrict__ whh,
                                                    const float* __restrict__ bih,
                                                    const float* __restrict__ bhh,
                                                    u16* __restrict__ hi, u16* __restrict__ lo,
                                                    float* __restrict__ bc)
{
  int np = blockIdx.x;            // 0..2047
  int d = np>>2, q = np&3;
  int orow = q*512 + d;
  for (int k = threadIdx.x; k < 1024; k += 256){
    float v = (k < 512) ? wih[(size_t)orow*512 + k] : whh[(size_t)orow*512 + (k-512)];
    u16 h = f2bf(v), l2 = f2bf(v - bf2f(h));
    size_t off = (((size_t)(k>>4)*64 + (np>>5))*64 + ((k>>3)&1)*32 + (np&31))*8 + (k&7);
    hi[off] = h; lo[off] = l2;
  }
  if (threadIdx.x == 0) bc[np] = bih[orow] + bhh[orow];
}

// ============ emb GEMM (A fp32, in-kernel split) =============================
__global__ __launch_bounds__(256) void gemm_emb(
    const float* __restrict__ A, const u16* __restrict__ Whi, const u16* __restrict__ Wlo,
    const float* __restrict__ bias, float* __restrict__ out, int K)
{
  __shared__ u16 Ah[128][40];
  __shared__ u16 Al[128][40];
  __shared__ u16 Wh[128][40];
  __shared__ u16 Wl[128][40];

  int bx = blockIdx.x;
  int nt = bx & 3, mt = bx >> 2;
  int m0 = mt*128, n0 = nt*128;
  int tid = threadIdx.x, lane = tid & 63, w = tid >> 6;
  int wm = (w>>1)*64, wn = (w&1)*64;

  f32x4 acc[4][4];
  #pragma unroll
  for (int i=0;i<4;i++)
    #pragma unroll
    for (int j=0;j<4;j++) acc[i][j] = (f32x4){0.f,0.f,0.f,0.f};

  for (int k0=0; k0<K; k0+=32){
    #pragma unroll
    for (int p=0;p<4;p++){
      int fi = p*256 + tid;
      int r = fi>>3, c = fi&7;
      float4 v = *(const float4*)&A[(size_t)(m0+r)*K + k0 + c*4];
      u16 h0=f2bf(v.x), h1=f2bf(v.y), h2=f2bf(v.z), h3=f2bf(v.w);
      u16 l0=f2bf(v.x-bf2f(h0)), l1=f2bf(v.y-bf2f(h1)), l2=f2bf(v.z-bf2f(h2)), l3=f2bf(v.w-bf2f(h3));
      uint2 ph = { (unsigned)h0 | ((unsigned)h1<<16), (unsigned)h2 | ((unsigned)h3<<16) };
      uint2 pl = { (unsigned)l0 | ((unsigned)l1<<16), (unsigned)l2 | ((unsigned)l3<<16) };
      *(uint2*)&Ah[r][c*4] = ph;
      *(uint2*)&Al[r][c*4] = pl;
    }
    #pragma unroll
    for (int p=0;p<2;p++){
      int fi = p*256 + tid;
      int r = fi>>2, c = fi&3;
      uint4 vh = *(const uint4*)&Whi[(size_t)(n0+r)*K + k0 + c*8];
      uint4 vl = *(const uint4*)&Wlo[(size_t)(n0+r)*K + k0 + c*8];
      *(uint4*)&Wh[r][c*8] = vh;
      *(uint4*)&Wl[r][c*8] = vl;
    }
    __syncthreads();
    s16x8 ah[4], al[4];
    #pragma unroll
    for (int mf=0;mf<4;mf++){
      ah[mf] = *(const s16x8*)&Ah[wm + mf*16 + (lane&15)][(lane>>4)*8];
      al[mf] = *(const s16x8*)&Al[wm + mf*16 + (lane&15)][(lane>>4)*8];
    }
    #pragma unroll
    for (int nf=0;nf<4;nf++){
      s16x8 wh = *(const s16x8*)&Wh[wn + nf*16 + (lane&15)][(lane>>4)*8];
      s16x8 wl = *(const s16x8*)&Wl[wn + nf*16 + (lane&15)][(lane>>4)*8];
      #pragma unroll
      for (int mf=0;mf<4;mf++){
        acc[mf][nf] = __builtin_amdgcn_mfma_f32_16x16x32_bf16(ah[mf], wh, acc[mf][nf], 0,0,0);
        acc[mf][nf] = __builtin_amdgcn_mfma_f32_16x16x32_bf16(ah[mf], wl, acc[mf][nf], 0,0,0);
        acc[mf][nf] = __builtin_amdgcn_mfma_f32_16x16x32_bf16(al[mf], wh, acc[mf][nf], 0,0,0);
      }
    }
    __syncthreads();
  }
  #pragma unroll
  for (int mf=0;mf<4;mf++){
    #pragma unroll
    for (int nf=0;nf<4;nf++){
      int col = n0 + wn + nf*16 + (lane&15);
      int row0 = m0 + wm + mf*16 + (lane>>4)*4;
      float b = bias[col];
      #pragma unroll
      for (int g=0; g<4; ++g){
        out[(size_t)(row0+g)*512 + col] = acc[mf][nf][g] + b;
      }
    }
  }
}

// ============ BN ==============================================================
__global__ __launch_bounds__(256) void bn_stats1(const float* __restrict__ Y,
                                                 float* __restrict__ psum,
                                                 float* __restrict__ psq)
{
  int blk = blockIdx.x;
  int tid = threadIdx.x;
  const float* base = Y + (size_t)blk*256*512;
  float sx=0.f, sy=0.f, qx=0.f, qy=0.f;
  for (int r=0;r<256;r++){
    float2 v = *(const float2*)&base[(size_t)r*512 + tid*2];
    sx += v.x; sy += v.y; qx += v.x*v.x; qy += v.y*v.y;
  }
  psum[(size_t)blk*512 + tid*2]   = sx;
  psum[(size_t)blk*512 + tid*2+1] = sy;
  psq [(size_t)blk*512 + tid*2]   = qx;
  psq [(size_t)blk*512 + tid*2+1] = qy;
}

__global__ __launch_bounds__(512) void bn_stats2(const float* __restrict__ psum,
                                                 const float* __restrict__ psq,
                                                 float* __restrict__ mean,
                                                 float* __restrict__ scale)
{
  int c = threadIdx.x;
  float s=0.f, q=0.f;
  for (int b=0;b<128;b++){ s += psum[(size_t)b*512+c]; q += psq[(size_t)b*512+c]; }
  float mu = s * (1.0f/32768.0f);
  float var = q * (1.0f/32768.0f) - mu*mu;
  mean[c] = mu;
  scale[c] = rsqrtf(var + 1e-5f);
}

// BN+ReLU, split to hi/lo, write frag-layout e planes (row r=b*256+t -> slot t, row b)
__global__ __launch_bounds__(256) void bn_apply_split(const float* __restrict__ Y,
                                                      const float* __restrict__ mean,
                                                      const float* __restrict__ scale,
                                                      const float* __restrict__ gamma,
                                                      const float* __restrict__ beta,
                                                      u16* __restrict__ ehi, u16* __restrict__ elo)
{
  size_t idx = (size_t)blockIdx.x*256 + threadIdx.x;  // 32768*64
  int r = (int)(idx >> 6);
  int c0 = (int)(idx & 63) * 8;
  int b = r >> 8, t = r & 255;
  float4 v0 = *(const float4*)&Y[(size_t)r*512 + c0];
  float4 v1 = *(const float4*)&Y[(size_t)r*512 + c0 + 4];
  float vv[8] = {v0.x,v0.y,v0.z,v0.w,v1.x,v1.y,v1.z,v1.w};
  unsigned int hw[4], lw[4];
  #pragma unroll
  for (int u=0;u<8;u+=2){
    float xa = fmaxf((vv[u]  -mean[c0+u])  *scale[c0+u]  *gamma[c0+u]  +beta[c0+u],   0.f);
    float xb = fmaxf((vv[u+1]-mean[c0+u+1])*scale[c0+u+1]*gamma[c0+u+1]+beta[c0+u+1], 0.f);
    u16 ha = f2bf(xa), hb = f2bf(xb);
    u16 la = f2bf(xa - bf2f(ha)), lb = f2bf(xb - bf2f(hb));
    hw[u>>1] = (unsigned)ha | ((unsigned)hb<<16);
    lw[u>>1] = (unsigned)la | ((unsigned)lb<<16);
  }
  size_t off = (size_t)t*65536 + ((((size_t)(c0>>4)*4 + (b>>5))*64) + ((c0>>3)&1)*32 + (b&31))*8;
  uint4 ph = {hw[0],hw[1],hw[2],hw[3]};
  uint4 pl = {lw[0],lw[1],lw[2],lw[3]};
  *(uint4*)&ehi[off] = ph;
  *(uint4*)&elo[off] = pl;
}

// ============ barrier + H-slot0 init =========================================
__global__ __launch_bounds__(256) void zero_init(int* __restrict__ bar,
                                                 unsigned* __restrict__ H0,
                                                 unsigned* __restrict__ H1)
{
  int i = blockIdx.x*256 + threadIdx.x;   // 256 blocks -> 65536 threads
  if (i < 6144) bar[i] = 0;               // flags[4][64][16] + gen[4][32][16]
  H0[i] = 0u;
  H1[i] = 0u;
}

// ============ persistent scan: r15 + LDS-staged coalesced h publish ==========
// 256 blocks = cell(2) x strip(64 of 32 permuted cols) x rowhalf(2 of 64 rows).
// Barrier domain = (cell,rowhalf): 4 independent groups of 64 blocks.
// h publish: epilogue -> 2KB LDS tile -> barrier -> ALL 4 waves store two
// contiguous 1KB chunks with 256 coalesced 8B device-scope stores. sig
// target 4/step. Barrier/master/gen protocol unchanged from r15.
struct ScanArgs {
  const u16 *e0hi, *e0lo, *e1hi, *e1lo;
  const u16 *wr0hi, *wr0lo, *wr1hi, *wr1lo;
  const float *bc0, *bc1, *mask;
  unsigned *H0, *H1;
  int *flags;   // [4][64][16]
  int *gen;     // [4][32][16]
};

__global__ __launch_bounds__(256) void scan_all(ScanArgs A)
{
  __shared__ u16 Wlds[64][64][8];        // 64 KB: W-hi [ksub][lane][8]
  __shared__ float red[2][2][16][65];    // 16.6 KB [phase][pair][elem][lane]
  __shared__ unsigned hstage[2][256];    // 2 KB staged h (two 1KB chunks)
  __shared__ int sig;                    // monotonic, +4 per step
  __shared__ int fcnt;                   // master: monotonic, +63 per step

  int bx = blockIdx.x;
  int ci = bx>>7, s = (bx>>1)&63, rh = bx&1;
  int dom = ci*2 + rh;                   // barrier domain (cell,rowhalf)
  int cb = s;                            // block index within domain (0..63)
  int tid = threadIdx.x, lane = tid&63, w = tid>>6;
  int khalf = w>>1, pr = w&1;
  int rt = rh*2 + pr;
  bool mast = (cb == 0);

  int* flags = A.flags + dom*64*16;
  int* gen   = A.gen   + dom*32*16;

  const u16* ehi = ci? A.e1hi : A.e0hi;
  const u16* elo = ci? A.e1lo : A.e0lo;
  const u16* whi = ci? A.wr1hi : A.wr0hi;
  const u16* wlo = ci? A.wr1lo : A.wr0lo;
  const float* bc = ci? A.bc1 : A.bc0;
  unsigned* Hc = ci? A.H1 : A.H0;

  if (tid == 0){ sig = 0; fcnt = 0; }

  // stage W-hi strip into LDS (once): [ks][ct=s][lane][8]
  for (int it=0; it<16; ++it){
    int cid = it*256 + tid;
    int ks = cid>>6, l8 = cid&63;
    const u16* src = whi + (((size_t)ks*64 + s)*64 + l8)*8;
    *(uint4*)&Wlds[ks][l8][0] = *(const uint4*)src;
  }
  __syncthreads();

  int q = lane&3;
  int np = s*32 + (lane&31);
  int d  = np>>2;
  float bcv = bc[np];
  float creg[4] = {0.f,0.f,0.f,0.f};    // c-state (H-waves)

  // block's two contiguous 1KB chunk bases (u32 index units), chunk c=pr slot
  // chunkBase(c) = ((s>>1)*4 + 2*rh + c)*512 + (s&1)*256
  int cbase0 = ((s>>1)*4 + 2*rh)*512 + (s&1)*256;

  for (int t=0; t<256; ++t){
    size_t abase = (size_t)t*65536;

    if (khalf == 0){
      // ---- e-waves: no wait, compute and hand off partials ----
      f32x16 a0=(f32x16)(0.f), a1=(f32x16)(0.f), a2=(f32x16)(0.f);
      #pragma unroll 4
      for (int kk=0; kk<32; ++kk){
        size_t aoff = abase + ((size_t)(kk*4 + rt)*64 + lane)*8;
        s16x8 fah = *(const s16x8*)(ehi + aoff);
        s16x8 fal = *(const s16x8*)(elo + aoff);
        s16x8 fwh = *(const s16x8*)&Wlds[kk][lane][0];
        s16x8 fwl = *(const s16x8*)(wlo + (((size_t)kk*64 + s)*64 + lane)*8);
        a0 = __builtin_amdgcn_mfma_f32_32x32x16_bf16(fah, fwh, a0, 0,0,0);
        a1 = __builtin_amdgcn_mfma_f32_32x32x16_bf16(fah, fwl, a1, 0,0,0);
        a2 = __builtin_amdgcn_mfma_f32_32x32x16_bf16(fal, fwh, a2, 0,0,0);
      }
      f32x16 t3 = a0 + a1 + a2;
      #pragma unroll
      for (int e=0;e<16;e++) red[t&1][pr][e][lane] = t3[e];
      __syncthreads();                 // #1
      __syncthreads();                 // #2 (hstage ready)
    } else {
      // ---- H-waves: wait for H slot t (gen >= t), compute, epilogue ----
      if (lane == 0){
        while (__hip_atomic_load(&gen[(cb&31)*16], __ATOMIC_RELAXED, __HIP_MEMORY_SCOPE_AGENT) < t)
          __builtin_amdgcn_s_sleep(1);
      }
      asm volatile("" ::: "memory");   // no load hoisting above the wait

      f32x16 a0=(f32x16)(0.f), a1=(f32x16)(0.f), a2=(f32x16)(0.f);
      #pragma unroll 8
      for (int kk=0; kk<32; ++kk){
        size_t aoff = abase + ((size_t)(kk*4 + rt)*64 + lane)*8;
        s16x8 fah, fal;
        unpack8(Hc + aoff, fah, fal);
        int ks = 32 + kk;
        s16x8 fwh = *(const s16x8*)&Wlds[ks][lane][0];
        s16x8 fwl = *(const s16x8*)(wlo + (((size_t)ks*64 + s)*64 + lane)*8);
        a0 = __builtin_amdgcn_mfma_f32_32x32x16_bf16(fah, fwh, a0, 0,0,0);
        a1 = __builtin_amdgcn_mfma_f32_32x32x16_bf16(fah, fwl, a1, 0,0,0);
        a2 = __builtin_amdgcn_mfma_f32_32x32x16_bf16(fal, fwh, a2, 0,0,0);
      }
      f32x16 mine = a0 + a1 + a2;
      __syncthreads();                 // #1: e-partials of step t ready

      f32x16 tot;
      #pragma unroll
      for (int e=0;e<16;e++) tot[e] = mine[e] + red[t&1][pr][e][lane];

      #pragma unroll
      for (int r=0;r<16;r++){
        float pre = tot[r] + bcv;
        float act = (q==2) ? tanhf(pre) : sigmoidf_(pre);
        float v1 = __shfl_xor(act, 1);
        float v2 = __shfl_xor(act, 2);
        float v3 = __shfl_xor(v1, 2);
        float gi = (q==0)? act : (q==1)? v1 : (q==2)? v2 : v3;
        float gf = (q==1)? act : (q==0)? v1 : (q==3)? v2 : v3;
        float gg = (q==2)? act : (q==3)? v1 : (q==0)? v2 : v3;
        float go = (q==3)? act : (q==2)? v1 : (q==1)? v2 : v3;
        if (q == (r&3)){
          int ri = r>>2;
          int rowl = q + 8*ri + 4*(lane>>5);          // row & 31
          float cold = creg[ri];
          float cn = gf*cold + gi*gg;
          float h  = go*tanhf(cn);
          int row = rh*64 + pr*32 + rowl;
          float mv = A.mask[(size_t)row*256 + t];
          cn *= mv; h *= mv;
          creg[ri] = cn;
          u16 hh = f2bf(h), hl = f2bf(h - bf2f(hh));
          hstage[pr][rowl*8 + ((lane&31)>>2)] = ((unsigned)hh<<16) | (unsigned)hl;
        }
      }
      __syncthreads();                 // #2: hstage complete
    }

    // ---- all 4 waves: coalesced device-scope store of hstage (2KB) ----
    {
      size_t hSlot = (size_t)(t+1)*65536;
      int i = tid;                     // 0..255, one u64 each
      int chunk = i>>7, within = i&127;
      u64 val = ((const u64*)&hstage[chunk][0])[within];
      size_t dst = hSlot + (size_t)cbase0 + (size_t)chunk*512 + (size_t)within*2;
      __hip_atomic_store((u64*)(Hc + dst), val, __ATOMIC_RELAXED, __HIP_MEMORY_SCOPE_AGENT);
    }
    asm volatile("s_waitcnt vmcnt(0)" ::: "memory");   // stores at LLC
    if (lane == 0) atomicAdd(&sig, 1);

    if (khalf == 1){
      if (mast){
        int fi = tid - 128;            // wave2: 0..63, wave3: 64..127
        if (fi >= 1 && fi < 64){
          while (__hip_atomic_load(&flags[fi*16], __ATOMIC_RELAXED, __HIP_MEMORY_SCOPE_AGENT) < t+1)
            __builtin_amdgcn_s_sleep(1);
          atomicAdd(&fcnt, 1);
        }
        if (tid == 128){
          while (__hip_atomic_load(&sig, __ATOMIC_RELAXED, __HIP_MEMORY_SCOPE_WORKGROUP) < 4*(t+1))
            __builtin_amdgcn_s_sleep(1);
          while (__hip_atomic_load(&fcnt, __ATOMIC_RELAXED, __HIP_MEMORY_SCOPE_WORKGROUP) < 63*(t+1))
            __builtin_amdgcn_s_sleep(1);
        }
        if (w == 2 && lane < 32){      // after lane0's spins (wave-ordered)
          atomicExch(&gen[lane*16], t+1);
        }
      } else {
        if (tid == 128){
          while (__hip_atomic_load(&sig, __ATOMIC_RELAXED, __HIP_MEMORY_SCOPE_WORKGROUP) < 4*(t+1))
            __builtin_amdgcn_s_sleep(1);
          atomicExch(&flags[cb*16], t+1);
        }
      }
    }
  }
}

// ============ gate GEMM: A,Other = interleaved H; out = split g planes =======
__global__ __launch_bounds__(256,1) void gemm_gate(
    const unsigned* __restrict__ Aint,
    const u16* __restrict__ Whi,  const u16* __restrict__ Wlo,
    const float* __restrict__ bias,
    const unsigned* __restrict__ OtInt,
    u16* __restrict__ outHi, u16* __restrict__ outLo)
{
  int bx = blockIdx.x;
  int nt = bx & 7, mt = bx >> 3;
  int n0 = nt*64;
  int tid = threadIdx.x, lane = tid & 63, w = tid >> 6;
  size_t aBase = (size_t)mt*65536;

  f32x16 a0[2], a1[2], a2[2];
  #pragma unroll
  for (int c=0;c<2;c++){
    a0[c]=(f32x16)(0.f); a1[c]=(f32x16)(0.f); a2[c]=(f32x16)(0.f);
  }

  #pragma unroll 2
  for (int kk=0; kk<32; ++kk){
    size_t aoff = aBase + (((size_t)kk*4 + w)*64 + lane)*8;
    s16x8 fah, fal;
    unpack8(Aint + aoff, fah, fal);
    #pragma unroll
    for (int c=0;c<2;c++){
      size_t woff = (((size_t)kk*16 + nt*2 + c)*64 + lane)*8;
      s16x8 fwh = *(const s16x8*)(Whi + woff);
      s16x8 fwl = *(const s16x8*)(Wlo + woff);
      a0[c] = __builtin_amdgcn_mfma_f32_32x32x16_bf16(fah, fwh, a0[c], 0,0,0);
      a1[c] = __builtin_amdgcn_mfma_f32_32x32x16_bf16(fah, fwl, a1[c], 0,0,0);
      a2[c] = __builtin_amdgcn_mfma_f32_32x32x16_bf16(fal, fwh, a2[c], 0,0,0);
    }
  }

  #pragma unroll
  for (int c=0;c<2;c++){
    f32x16 acc = a0[c] + a1[c] + a2[c];
    int col = n0 + c*32 + (lane&31);
    float b = bias[col];
    #pragma unroll
    for (int r=0;r<16;r++){
      int row = w*32 + (r&3) + 8*(r>>2) + 4*(lane>>5);
      float v = acc[r] + b;
      size_t foff = aBase + ((((size_t)(col>>4)*4 + w)*64) + ((col>>3)&1)*32 + (row&31))*8 + (col&7);
      unsigned ov = OtInt[foff];
      float other = bf2f((u16)(ov>>16)) + bf2f((u16)(ov&0xffffu));
      v = sigmoidf_(v) * other;
      u16 hh = f2bf(v);
      u16 hl = f2bf(v - bf2f(hh));
      outHi[foff] = hh;
      outLo[foff] = hl;
    }
  }
}

// ============ final GEMM: dual split A pairs -> tanh f32 out =================
__global__ __launch_bounds__(256,1) void gemm_final(
    const u16* __restrict__ Ahi,  const u16* __restrict__ Alo,
    const u16* __restrict__ A2hi, const u16* __restrict__ A2lo,
    const u16* __restrict__ Whi,  const u16* __restrict__ Wlo,
    const u16* __restrict__ W2hi, const u16* __restrict__ W2lo,
    const float* __restrict__ bias,
    float* __restrict__ outF)
{
  int bx = blockIdx.x;
  int nt = bx & 7, mt = bx >> 3;
  int n0 = nt*64;
  int tid = threadIdx.x, lane = tid & 63, w = tid >> 6;
  size_t aBase = (size_t)mt*65536;

  f32x16 a0[2], a1[2], a2[2];
  #pragma unroll
  for (int c=0;c<2;c++){
    a0[c]=(f32x16)(0.f); a1[c]=(f32x16)(0.f); a2[c]=(f32x16)(0.f);
  }

  for (int pair=0; pair<2; ++pair){
    const u16* ah = pair ? A2hi : Ahi;
    const u16* al = pair ? A2lo : Alo;
    const u16* wh = pair ? W2hi : Whi;
    const u16* wl = pair ? W2lo : Wlo;
    #pragma unroll 2
    for (int kk=0; kk<32; ++kk){
      size_t aoff = aBase + (((size_t)kk*4 + w)*64 + lane)*8;
      s16x8 fah = *(const s16x8*)(ah + aoff);
      s16x8 fal = *(const s16x8*)(al + aoff);
      #pragma unroll
      for (int c=0;c<2;c++){
        size_t woff = (((size_t)kk*16 + nt*2 + c)*64 + lane)*8;
        s16x8 fwh = *(const s16x8*)(wh + woff);
        s16x8 fwl = *(const s16x8*)(wl + woff);
        a0[c] = __builtin_amdgcn_mfma_f32_32x32x16_bf16(fah, fwh, a0[c], 0,0,0);
        a1[c] = __builtin_amdgcn_mfma_f32_32x32x16_bf16(fah, fwl, a1[c], 0,0,0);
        a2[c] = __builtin_amdgcn_mfma_f32_32x32x16_bf16(fal, fwh, a2[c], 0,0,0);
      }
    }
  }

  #pragma unroll
  for (int c=0;c<2;c++){
    f32x16 acc = a0[c] + a1[c] + a2[c];
    int col = n0 + c*32 + (lane&31);
    float b = bias[col];
    #pragma unroll
    for (int r=0;r<16;r++){
      int row = w*32 + (r&3) + 8*(r>>2) + 4*(lane>>5);
      float v = tanhf(acc[r] + b);
      outF[((size_t)row*256 + mt)*512 + col] = v;
    }
  }
}

// ============ launch ==========================================================
extern "C" void kernel_launch(void* const* d_in, const int* in_sizes, int n_in,
                              void* d_out, int out_size, void* d_ws, size_t ws_size,
                              hipStream_t stream)
{
  const float* feat0  = (const float*)d_in[0];
  const float* feat1  = (const float*)d_in[1];
  const float* fmask  = (const float*)d_in[2];
  const float* w_emb0 = (const float*)d_in[3];
  const float* b_emb0 = (const float*)d_in[4];
  const float* gamma0 = (const float*)d_in[5];
  const float* beta0  = (const float*)d_in[6];
  const float* w_emb1 = (const float*)d_in[7];
  const float* b_emb1 = (const float*)d_in[8];
  const float* gamma1 = (const float*)d_in[9];
  const float* beta1  = (const float*)d_in[10];
  const float* w_ih0  = (const float*)d_in[11];
  const float* w_hh0  = (const float*)d_in[12];
  const float* b_ih0  = (const float*)d_in[13];
  const float* b_hh0  = (const float*)d_in[14];
  const float* w_ih1  = (const float*)d_in[15];
  const float* w_hh1  = (const float*)d_in[16];
  const float* b_ih1  = (const float*)d_in[17];
  const float* b_hh1  = (const float*)d_in[18];
  const float* wg0    = (const float*)d_in[19];
  const float* bg0    = (const float*)d_in[20];
  const float* wg1    = (const float*)d_in[21];
  const float* bg1    = (const float*)d_in[22];
  const float* wf1    = (const float*)d_in[23];
  const float* wf2    = (const float*)d_in[24];
  const float* bf     = (const float*)d_in[25];
  float* out = (float*)d_out;

  char* ws = (char*)d_ws;
  u16* e0hi = (u16*)(ws + 0);
  u16* e0lo = (u16*)(ws + 33554432);
  u16* e1hi = (u16*)(ws + 67108864);
  u16* e1lo = (u16*)(ws + 100663296);
  unsigned* H0int = (unsigned*)(ws + 134217728);
  unsigned* H1int = (unsigned*)(ws + 201588736);
  int*   barp  = (int*)(ws + 269484032);     // flags + gen (pre-scan region)
  float* psum  = (float*)(ws + 269484032);
  float* psq   = (float*)(ws + 269746176);
  float* meanb = (float*)(ws + 270008320);
  float* scaleb= (float*)(ws + 270010368);
  float* bc0   = (float*)(ws + 270012416);
  float* bc1   = (float*)(ws + 270020608);
  u16* wr0hi = (u16*)(ws + 270028800);
  u16* wr0lo = (u16*)(ws + 274223104);
  u16* wr1hi = (u16*)(ws + 278417408);
  u16* wr1lo = (u16*)(ws + 282611712);
  u16* we0hi = (u16*)(ws + 286806016);
  u16* we0lo = (u16*)(ws + 288903168);
  u16* we1hi = (u16*)(ws + 291000320);
  u16* we1lo = (u16*)(ws + 292048896);
  u16* wg0hi = (u16*)(ws + 293097472);
  u16* wg0lo = (u16*)(ws + 293621760);
  u16* wg1hi = (u16*)(ws + 294146048);
  u16* wg1lo = (u16*)(ws + 294670336);
  u16* wf1hi = (u16*)(ws + 295194624);
  u16* wf1lo = (u16*)(ws + 295718912);
  u16* wf2hi = (u16*)(ws + 296243200);
  u16* wf2lo = (u16*)(ws + 296767488);
  float* Ytmp = (float*)(ws + 134217728);   // aliases H0int, pre-scan only

  // ---- weight prep ----
  split_gates2<<<dim3(2048), dim3(256), 0, stream>>>(w_ih0, w_hh0, b_ih0, b_hh0, wr0hi, wr0lo, bc0);
  split_gates2<<<dim3(2048), dim3(256), 0, stream>>>(w_ih1, w_hh1, b_ih1, b_hh1, wr1hi, wr1lo, bc1);
  split_plain<<<dim3(4096), dim3(256), 0, stream>>>(w_emb0, we0hi, we0lo, 1048576);
  split_plain<<<dim3(2048), dim3(256), 0, stream>>>(w_emb1, we1hi, we1lo, 524288);
  split_fragW<<<dim3(1024), dim3(256), 0, stream>>>(wg0, wg0hi, wg0lo, 512, 512);
  split_fragW<<<dim3(1024), dim3(256), 0, stream>>>(wg1, wg1hi, wg1lo, 512, 512);
  split_fragW<<<dim3(1024), dim3(256), 0, stream>>>(wf1, wf1hi, wf1lo, 512, 512);
  split_fragW<<<dim3(1024), dim3(256), 0, stream>>>(wf2, wf2hi, wf2lo, 512, 512);

  // ---- embeddings + BN (Y temp in H0int region) ----
  gemm_emb<<<dim3(1024), dim3(256), 0, stream>>>(feat0, we0hi, we0lo, b_emb0, Ytmp, 2048);
  bn_stats1<<<dim3(128), dim3(256), 0, stream>>>(Ytmp, psum, psq);
  bn_stats2<<<dim3(1),   dim3(512), 0, stream>>>(psum, psq, meanb, scaleb);
  bn_apply_split<<<dim3(8192), dim3(256), 0, stream>>>(Ytmp, meanb, scaleb, gamma0, beta0, e0hi, e0lo);

  gemm_emb<<<dim3(1024), dim3(256), 0, stream>>>(feat1, we1hi, we1lo, b_emb1, Ytmp, 1024);
  bn_stats1<<<dim3(128), dim3(256), 0, stream>>>(Ytmp, psum, psq);
  bn_stats2<<<dim3(1),   dim3(512), 0, stream>>>(psum, psq, meanb, scaleb);
  bn_apply_split<<<dim3(8192), dim3(256), 0, stream>>>(Ytmp, meanb, scaleb, gamma1, beta1, e1hi, e1lo);

  // ---- persistent scan: 4 domains; LDS-staged coalesced h publish ----
  zero_init<<<dim3(256), dim3(256), 0, stream>>>(barp, H0int, H1int);
  ScanArgs sa;
  sa.e0hi=e0hi; sa.e0lo=e0lo; sa.e1hi=e1hi; sa.e1lo=e1lo;
  sa.wr0hi=wr0hi; sa.wr0lo=wr0lo; sa.wr1hi=wr1hi; sa.wr1lo=wr1lo;
  sa.bc0=bc0; sa.bc1=bc1; sa.mask=fmask;
  sa.H0=H0int; sa.H1=H1int;
  sa.flags=barp; sa.gen=barp + 4*64*16;
  scan_all<<<dim3(256), dim3(256), 0, stream>>>(sa);

  // ---- gate0 = sigmoid(h1@wg0^T+bg0)*h0 -> g0 planes (e0 region) ----
  gemm_gate<<<dim3(2048), dim3(256), 0, stream>>>(
      H1int + 65536, wg0hi, wg0lo, bg0, H0int + 65536, e0hi, e0lo);
  // ---- gate1 = sigmoid(h0@wg1^T+bg1)*h1 -> g1 planes (e1 region) ----
  gemm_gate<<<dim3(2048), dim3(256), 0, stream>>>(
      H0int + 65536, wg1hi, wg1lo, bg1, H1int + 65536, e1hi, e1lo);
  // ---- out = tanh(g0@wf1^T + g1@wf2^T + bf) ----
  gemm_final<<<dim3(2048), dim3(256), 0, stream>>>(
      e0hi, e0lo, e1hi, e1lo,
      wf1hi, wf1lo, wf2hi, wf2lo, bf, out);
}

// Round 17
// 7531.943 us; speedup vs baseline: 1.1989x; 1.1989x over previous
//
#include <hip/hip_runtime.h>
#include <math.h>

// Dims: B=128, T=256, D=512, F0=2048, F1=1024, R=B*T=32768
//
// ws layout (BYTE offsets):
//  e0hi @ 0, e0lo @ 33554432, e1hi @ 67108864, e1lo @ 100663296
//  H0int @ 134217728 (67371008 B: 257 slots x 65536 u32, (hi<<16)|lo)
//  H1int @ 201588736 (67371008 B)
//  bar  @ 269484032  flags[4][64][16] ints (pre-scan region)
//  psum @ 269484032, psq @ 269746176, mean @ 270008320, scl @ 270010368
//  bc0 @ 270012416, bc1 @ 270020608
//  wr0hi@ 270028800, wr0lo@ 274223104, wr1hi@ 278417408, wr1lo@ 282611712
//  we0hi@ 286806016, we0lo@ 288903168, we1hi@ 291000320, we1lo@ 292048896
//  wg0hi@ 293097472 .. wf2lo@ 296767488
//  Y temp (fp32 64MB) aliases H0int (pre-scan only).
//
// r17 = EXACT r15 (champion: 6.42ms scan) + ONE change: all-to-all flag wait.
// Master/gen/fcnt deleted; both H-waves poll flags[lane] >= t directly
// (one LLC notice hop instead of two). Publish path unchanged from r15.

typedef short s16x8 __attribute__((ext_vector_type(8)));
typedef float f32x4 __attribute__((ext_vector_type(4)));
typedef float f32x16 __attribute__((ext_vector_type(16)));
typedef unsigned short u16;

__device__ __forceinline__ float sigmoidf_(float x){ return 1.0f/(1.0f+expf(-x)); }

__device__ __forceinline__ u16 f2bf(float x){
  unsigned int u = __float_as_uint(x);
  unsigned int r = u + 0x7fffu + ((u>>16)&1u);
  return (u16)(r>>16);
}
__device__ __forceinline__ float bf2f(u16 s){ return __uint_as_float(((unsigned int)s)<<16); }

// unpack 8 interleaved u32 ((hi<<16)|lo) -> two s16x8 fragments
__device__ __forceinline__ void unpack8(const unsigned int* __restrict__ p,
                                        s16x8& hi, s16x8& lo){
  uint4 w0 = *(const uint4*)p;
  uint4 w1 = *(const uint4*)(p+4);
  union { unsigned int u[4]; s16x8 v; } H, L;
  H.u[0] = (w0.x>>16) | (w0.y & 0xffff0000u);
  H.u[1] = (w0.z>>16) | (w0.w & 0xffff0000u);
  H.u[2] = (w1.x>>16) | (w1.y & 0xffff0000u);
  H.u[3] = (w1.z>>16) | (w1.w & 0xffff0000u);
  L.u[0] = (w0.x & 0xffffu) | (w0.y<<16);
  L.u[1] = (w0.z & 0xffffu) | (w0.w<<16);
  L.u[2] = (w1.x & 0xffffu) | (w1.y<<16);
  L.u[3] = (w1.z & 0xffffu) | (w1.w<<16);
  hi = H.v; lo = L.v;
}

// ============ weight prep ====================================================
__global__ __launch_bounds__(256) void split_plain(const float* __restrict__ src,
                                                   u16* __restrict__ hi, u16* __restrict__ lo, int n)
{
  int i = blockIdx.x*256 + threadIdx.x;
  if (i < n){
    float v = src[i];
    u16 h = f2bf(v);
    hi[i] = h;
    lo[i] = f2bf(v - bf2f(h));
  }
}

__global__ __launch_bounds__(256) void split_fragW(const float* __restrict__ src,
                                                   u16* __restrict__ hi, u16* __restrict__ lo,
                                                   int N, int K)
{
  int i = blockIdx.x*256 + threadIdx.x;
  if (i >= N*K) return;
  int n = i / K, k = i - n*K;
  float v = src[i];
  u16 h = f2bf(v), l2 = f2bf(v - bf2f(h));
  size_t off = ((((size_t)(k>>4)*(N/32) + (n>>5))*64) + ((k>>3)&1)*32 + (n&31))*8 + (k&7);
  hi[off] = h; lo[off] = l2;
}

__global__ __launch_bounds__(256) void split_gates2(const float* __restrict__ wih,
                                                    const float* __restrict__ whh,
                                                    const float* __restrict__ bih,
                                                    const float* __restrict__ bhh,
                                                    u16* __restrict__ hi, u16* __restrict__ lo,
                                                    float* __restrict__ bc)
{
  int np = blockIdx.x;            // 0..2047
  int d = np>>2, q = np&3;
  int orow = q*512 + d;
  for (int k = threadIdx.x; k < 1024; k += 256){
    float v = (k < 512) ? wih[(size_t)orow*512 + k] : whh[(size_t)orow*512 + (k-512)];
    u16 h = f2bf(v), l2 = f2bf(v - bf2f(h));
    size_t off = (((size_t)(k>>4)*64 + (np>>5))*64 + ((k>>3)&1)*32 + (np&31))*8 + (k&7);
    hi[off] = h; lo[off] = l2;
  }
  if (threadIdx.x == 0) bc[np] = bih[orow] + bhh[orow];
}

// ============ emb GEMM (A fp32, in-kernel split) =============================
__global__ __launch_bounds__(256) void gemm_emb(
    const float* __restrict__ A, const u16* __restrict__ Whi, const u16* __restrict__ Wlo,
    const float* __restrict__ bias, float* __restrict__ out, int K)
{
  __shared__ u16 Ah[128][40];
  __shared__ u16 Al[128][40];
  __shared__ u16 Wh[128][40];
  __shared__ u16 Wl[128][40];

  int bx = blockIdx.x;
  int nt = bx & 3, mt = bx >> 2;
  int m0 = mt*128, n0 = nt*128;
  int tid = threadIdx.x, lane = tid & 63, w = tid >> 6;
  int wm = (w>>1)*64, wn = (w&1)*64;

  f32x4 acc[4][4];
  #pragma unroll
  for (int i=0;i<4;i++)
    #pragma unroll
    for (int j=0;j<4;j++) acc[i][j] = (f32x4){0.f,0.f,0.f,0.f};

  for (int k0=0; k0<K; k0+=32){
    #pragma unroll
    for (int p=0;p<4;p++){
      int fi = p*256 + tid;
      int r = fi>>3, c = fi&7;
      float4 v = *(const float4*)&A[(size_t)(m0+r)*K + k0 + c*4];
      u16 h0=f2bf(v.x), h1=f2bf(v.y), h2=f2bf(v.z), h3=f2bf(v.w);
      u16 l0=f2bf(v.x-bf2f(h0)), l1=f2bf(v.y-bf2f(h1)), l2=f2bf(v.z-bf2f(h2)), l3=f2bf(v.w-bf2f(h3));
      uint2 ph = { (unsigned)h0 | ((unsigned)h1<<16), (unsigned)h2 | ((unsigned)h3<<16) };
      uint2 pl = { (unsigned)l0 | ((unsigned)l1<<16), (unsigned)l2 | ((unsigned)l3<<16) };
      *(uint2*)&Ah[r][c*4] = ph;
      *(uint2*)&Al[r][c*4] = pl;
    }
    #pragma unroll
    for (int p=0;p<2;p++){
      int fi = p*256 + tid;
      int r = fi>>2, c = fi&3;
      uint4 vh = *(const uint4*)&Whi[(size_t)(n0+r)*K + k0 + c*8];
      uint4 vl = *(const uint4*)&Wlo[(size_t)(n0+r)*K + k0 + c*8];
      *(uint4*)&Wh[r][c*8] = vh;
      *(uint4*)&Wl[r][c*8] = vl;
    }
    __syncthreads();
    s16x8 ah[4], al[4];
    #pragma unroll
    for (int mf=0;mf<4;mf++){
      ah[mf] = *(const s16x8*)&Ah[wm + mf*16 + (lane&15)][(lane>>4)*8];
      al[mf] = *(const s16x8*)&Al[wm + mf*16 + (lane&15)][(lane>>4)*8];
    }
    #pragma unroll
    for (int nf=0;nf<4;nf++){
      s16x8 wh = *(const s16x8*)&Wh[wn + nf*16 + (lane&15)][(lane>>4)*8];
      s16x8 wl = *(const s16x8*)&Wl[wn + nf*16 + (lane&15)][(lane>>4)*8];
      #pragma unroll
      for (int mf=0;mf<4;mf++){
        acc[mf][nf] = __builtin_amdgcn_mfma_f32_16x16x32_bf16(ah[mf], wh, acc[mf][nf], 0,0,0);
        acc[mf][nf] = __builtin_amdgcn_mfma_f32_16x16x32_bf16(ah[mf], wl, acc[mf][nf], 0,0,0);
        acc[mf][nf] = __builtin_amdgcn_mfma_f32_16x16x32_bf16(al[mf], wh, acc[mf][nf], 0,0,0);
      }
    }
    __syncthreads();
  }
  #pragma unroll
  for (int mf=0;mf<4;mf++){
    #pragma unroll
    for (int nf=0;nf<4;nf++){
      int col = n0 + wn + nf*16 + (lane&15);
      int row0 = m0 + wm + mf*16 + (lane>>4)*4;
      float b = bias[col];
      #pragma unroll
      for (int g=0; g<4; ++g){
        out[(size_t)(row0+g)*512 + col] = acc[mf][nf][g] + b;
      }
    }
  }
}

// ============ BN ==============================================================
__global__ __launch_bounds__(256) void bn_stats1(const float* __restrict__ Y,
                                                 float* __restrict__ psum,
                                                 float* __restrict__ psq)
{
  int blk = blockIdx.x;
  int tid = threadIdx.x;
  const float* base = Y + (size_t)blk*256*512;
  float sx=0.f, sy=0.f, qx=0.f, qy=0.f;
  for (int r=0;r<256;r++){
    float2 v = *(const float2*)&base[(size_t)r*512 + tid*2];
    sx += v.x; sy += v.y; qx += v.x*v.x; qy += v.y*v.y;
  }
  psum[(size_t)blk*512 + tid*2]   = sx;
  psum[(size_t)blk*512 + tid*2+1] = sy;
  psq [(size_t)blk*512 + tid*2]   = qx;
  psq [(size_t)blk*512 + tid*2+1] = qy;
}

__global__ __launch_bounds__(512) void bn_stats2(const float* __restrict__ psum,
                                                 const float* __restrict__ psq,
                                                 float* __restrict__ mean,
                                                 float* __restrict__ scale)
{
  int c = threadIdx.x;
  float s=0.f, q=0.f;
  for (int b=0;b<128;b++){ s += psum[(size_t)b*512+c]; q += psq[(size_t)b*512+c]; }
  float mu = s * (1.0f/32768.0f);
  float var = q * (1.0f/32768.0f) - mu*mu;
  mean[c] = mu;
  scale[c] = rsqrtf(var + 1e-5f);
}

// BN+ReLU, split to hi/lo, write frag-layout e planes (row r=b*256+t -> slot t, row b)
__global__ __launch_bounds__(256) void bn_apply_split(const float* __restrict__ Y,
                                                      const float* __restrict__ mean,
                                                      const float* __restrict__ scale,
                                                      const float* __restrict__ gamma,
                                                      const float* __restrict__ beta,
                                                      u16* __restrict__ ehi, u16* __restrict__ elo)
{
  size_t idx = (size_t)blockIdx.x*256 + threadIdx.x;  // 32768*64
  int r = (int)(idx >> 6);
  int c0 = (int)(idx & 63) * 8;
  int b = r >> 8, t = r & 255;
  float4 v0 = *(const float4*)&Y[(size_t)r*512 + c0];
  float4 v1 = *(const float4*)&Y[(size_t)r*512 + c0 + 4];
  float vv[8] = {v0.x,v0.y,v0.z,v0.w,v1.x,v1.y,v1.z,v1.w};
  unsigned int hw[4], lw[4];
  #pragma unroll
  for (int u=0;u<8;u+=2){
    float xa = fmaxf((vv[u]  -mean[c0+u])  *scale[c0+u]  *gamma[c0+u]  +beta[c0+u],   0.f);
    float xb = fmaxf((vv[u+1]-mean[c0+u+1])*scale[c0+u+1]*gamma[c0+u+1]+beta[c0+u+1], 0.f);
    u16 ha = f2bf(xa), hb = f2bf(xb);
    u16 la = f2bf(xa - bf2f(ha)), lb = f2bf(xb - bf2f(hb));
    hw[u>>1] = (unsigned)ha | ((unsigned)hb<<16);
    lw[u>>1] = (unsigned)la | ((unsigned)lb<<16);
  }
  size_t off = (size_t)t*65536 + ((((size_t)(c0>>4)*4 + (b>>5))*64) + ((c0>>3)&1)*32 + (b&31))*8;
  uint4 ph = {hw[0],hw[1],hw[2],hw[3]};
  uint4 pl = {lw[0],lw[1],lw[2],lw[3]};
  *(uint4*)&ehi[off] = ph;
  *(uint4*)&elo[off] = pl;
}

// ============ barrier + H-slot0 init =========================================
__global__ __launch_bounds__(256) void zero_init(int* __restrict__ bar,
                                                 unsigned* __restrict__ H0,
                                                 unsigned* __restrict__ H1)
{
  int i = blockIdx.x*256 + threadIdx.x;   // 256 blocks -> 65536 threads
  if (i < 4096) bar[i] = 0;               // flags[4][64][16]
  H0[i] = 0u;
  H1[i] = 0u;
}

// ============ persistent scan: r15 + all-to-all flag wait ====================
// 256 blocks = cell(2) x strip(64 of 32 permuted cols) x rowhalf(2 of 64 rows).
// Barrier domain = (cell,rowhalf): 4 independent groups of 64 blocks.
// Wait: BOTH H-waves poll flags[lane] >= t directly (64 flags, one per lane,
// wave-converged exit) — one LLC notice hop; no master, no gen.
// Publish: epilogue-interleaved scattered atomicExch (r15 path); tid==128
// sets flags[cb]=t+1 after sig==2(t+1).
struct ScanArgs {
  const u16 *e0hi, *e0lo, *e1hi, *e1lo;
  const u16 *wr0hi, *wr0lo, *wr1hi, *wr1lo;
  const float *bc0, *bc1, *mask;
  unsigned *H0, *H1;
  int *flags;   // [4][64][16]
};

__global__ __launch_bounds__(256) void scan_all(ScanArgs A)
{
  __shared__ u16 Wlds[64][64][8];        // 64 KB: W-hi [ksub][lane][8]
  __shared__ float red[2][2][16][65];    // 16.6 KB [phase][pair][elem][lane]
  __shared__ int sig;                    // monotonic, +2 per step

  int bx = blockIdx.x;
  int ci = bx>>7, s = (bx>>1)&63, rh = bx&1;
  int dom = ci*2 + rh;                   // barrier domain (cell,rowhalf)
  int cb = s;                            // block index within domain (0..63)
  int tid = threadIdx.x, lane = tid&63, w = tid>>6;
  int khalf = w>>1, pr = w&1;
  int rt = rh*2 + pr;

  int* flags = A.flags + dom*64*16;

  const u16* ehi = ci? A.e1hi : A.e0hi;
  const u16* elo = ci? A.e1lo : A.e0lo;
  const u16* whi = ci? A.wr1hi : A.wr0hi;
  const u16* wlo = ci? A.wr1lo : A.wr0lo;
  const float* bc = ci? A.bc1 : A.bc0;
  unsigned* Hc = ci? A.H1 : A.H0;

  if (tid == 0) sig = 0;

  // stage W-hi strip into LDS (once): [ks][ct=s][lane][8]
  for (int it=0; it<16; ++it){
    int cid = it*256 + tid;
    int ks = cid>>6, l8 = cid&63;
    const u16* src = whi + (((size_t)ks*64 + s)*64 + l8)*8;
    *(uint4*)&Wlds[ks][l8][0] = *(const uint4*)src;
  }
  __syncthreads();

  int q = lane&3;
  int np = s*32 + (lane&31);
  int d  = np>>2;
  float bcv = bc[np];
  float creg[4] = {0.f,0.f,0.f,0.f};    // c-state (H-waves)

  for (int t=0; t<256; ++t){
    size_t abase = (size_t)t*65536;

    if (khalf == 0){
      // ---- e-waves: no wait, compute and hand off partials ----
      f32x16 a0=(f32x16)(0.f), a1=(f32x16)(0.f), a2=(f32x16)(0.f);
      #pragma unroll 4
      for (int kk=0; kk<32; ++kk){
        size_t aoff = abase + ((size_t)(kk*4 + rt)*64 + lane)*8;
        s16x8 fah = *(const s16x8*)(ehi + aoff);
        s16x8 fal = *(const s16x8*)(elo + aoff);
        s16x8 fwh = *(const s16x8*)&Wlds[kk][lane][0];
        s16x8 fwl = *(const s16x8*)(wlo + (((size_t)kk*64 + s)*64 + lane)*8);
        a0 = __builtin_amdgcn_mfma_f32_32x32x16_bf16(fah, fwh, a0, 0,0,0);
        a1 = __builtin_amdgcn_mfma_f32_32x32x16_bf16(fah, fwl, a1, 0,0,0);
        a2 = __builtin_amdgcn_mfma_f32_32x32x16_bf16(fal, fwh, a2, 0,0,0);
      }
      f32x16 t3 = a0 + a1 + a2;
      #pragma unroll
      for (int e=0;e<16;e++) red[t&1][pr][e][lane] = t3[e];
      __syncthreads();
    } else {
      // ---- H-waves: all-to-all wait (one flag per lane), compute, finish ----
      {
        int v;
        do {
          v = __hip_atomic_load(&flags[lane*16], __ATOMIC_RELAXED, __HIP_MEMORY_SCOPE_AGENT);
          if (v < t) __builtin_amdgcn_s_sleep(1);
        } while (v < t);
      }
      asm volatile("" ::: "memory");   // no load hoisting above the wait

      f32x16 a0=(f32x16)(0.f), a1=(f32x16)(0.f), a2=(f32x16)(0.f);
      #pragma unroll 8
      for (int kk=0; kk<32; ++kk){
        size_t aoff = abase + ((size_t)(kk*4 + rt)*64 + lane)*8;
        s16x8 fah, fal;
        unpack8(Hc + aoff, fah, fal);
        int ks = 32 + kk;
        s16x8 fwh = *(const s16x8*)&Wlds[ks][lane][0];
        s16x8 fwl = *(const s16x8*)(wlo + (((size_t)ks*64 + s)*64 + lane)*8);
        a0 = __builtin_amdgcn_mfma_f32_32x32x16_bf16(fah, fwh, a0, 0,0,0);
        a1 = __builtin_amdgcn_mfma_f32_32x32x16_bf16(fah, fwl, a1, 0,0,0);
        a2 = __builtin_amdgcn_mfma_f32_32x32x16_bf16(fal, fwh, a2, 0,0,0);
      }
      f32x16 mine = a0 + a1 + a2;
      __syncthreads();                 // e-partials of step t ready in red[t&1]

      f32x16 tot;
      #pragma unroll
      for (int e=0;e<16;e++) tot[e] = mine[e] + red[t&1][pr][e][lane];

      size_t hSlot = (size_t)(t+1)*65536;
      #pragma unroll
      for (int r=0;r<16;r++){
        float pre = tot[r] + bcv;
        float act = (q==2) ? tanhf(pre) : sigmoidf_(pre);
        float v1 = __shfl_xor(act, 1);
        float v2 = __shfl_xor(act, 2);
        float v3 = __shfl_xor(v1, 2);
        float gi = (q==0)? act : (q==1)? v1 : (q==2)? v2 : v3;
        float gf = (q==1)? act : (q==0)? v1 : (q==3)? v2 : v3;
        float gg = (q==2)? act : (q==3)? v1 : (q==0)? v2 : v3;
        float go = (q==3)? act : (q==2)? v1 : (q==1)? v2 : v3;
        if (q == (r&3)){
          int ri = r>>2;
          int row = rh*64 + pr*32 + (r&3) + 8*ri + 4*(lane>>5);
          float cold = creg[ri];
          float cn = gf*cold + gi*gg;
          float h  = go*tanhf(cn);
          float mv = A.mask[(size_t)row*256 + t];
          cn *= mv; h *= mv;
          creg[ri] = cn;
          u16 hh = f2bf(h), hl = f2bf(h - bf2f(hh));
          size_t hoff = hSlot + ((((size_t)(d>>4)*4 + (row>>5))*64) + ((d>>3)&1)*32 + (row&31))*8 + (d&7);
          atomicExch(&Hc[hoff], ((unsigned)hh<<16) | (unsigned)hl);   // LLC-resident
        }
      }
      asm volatile("s_waitcnt vmcnt(0)" ::: "memory");  // atomics executed at LLC
      if (lane == 0) atomicAdd(&sig, 1);
      if (tid == 128){
        while (__hip_atomic_load(&sig, __ATOMIC_RELAXED, __HIP_MEMORY_SCOPE_WORKGROUP) < 2*(t+1))
          __builtin_amdgcn_s_sleep(1);
        atomicExch(&flags[cb*16], t+1);
      }
    }
  }
}

// ============ gate GEMM: A,Other = interleaved H; out = split g planes =======
__global__ __launch_bounds__(256,1) void gemm_gate(
    const unsigned* __restrict__ Aint,
    const u16* __restrict__ Whi,  const u16* __restrict__ Wlo,
    const float* __restrict__ bias,
    const unsigned* __restrict__ OtInt,
    u16* __restrict__ outHi, u16* __restrict__ outLo)
{
  int bx = blockIdx.x;
  int nt = bx & 7, mt = bx >> 3;
  int n0 = nt*64;
  int tid = threadIdx.x, lane = tid & 63, w = tid >> 6;
  size_t aBase = (size_t)mt*65536;

  f32x16 a0[2], a1[2], a2[2];
  #pragma unroll
  for (int c=0;c<2;c++){
    a0[c]=(f32x16)(0.f); a1[c]=(f32x16)(0.f); a2[c]=(f32x16)(0.f);
  }

  #pragma unroll 2
  for (int kk=0; kk<32; ++kk){
    size_t aoff = aBase + (((size_t)kk*4 + w)*64 + lane)*8;
    s16x8 fah, fal;
    unpack8(Aint + aoff, fah, fal);
    #pragma unroll
    for (int c=0;c<2;c++){
      size_t woff = (((size_t)kk*16 + nt*2 + c)*64 + lane)*8;
      s16x8 fwh = *(const s16x8*)(Whi + woff);
      s16x8 fwl = *(const s16x8*)(Wlo + woff);
      a0[c] = __builtin_amdgcn_mfma_f32_32x32x16_bf16(fah, fwh, a0[c], 0,0,0);
      a1[c] = __builtin_amdgcn_mfma_f32_32x32x16_bf16(fah, fwl, a1[c], 0,0,0);
      a2[c] = __builtin_amdgcn_mfma_f32_32x32x16_bf16(fal, fwh, a2[c], 0,0,0);
    }
  }

  #pragma unroll
  for (int c=0;c<2;c++){
    f32x16 acc = a0[c] + a1[c] + a2[c];
    int col = n0 + c*32 + (lane&31);
    float b = bias[col];
    #pragma unroll
    for (int r=0;r<16;r++){
      int row = w*32 + (r&3) + 8*(r>>2) + 4*(lane>>5);
      float v = acc[r] + b;
      size_t foff = aBase + ((((size_t)(col>>4)*4 + w)*64) + ((col>>3)&1)*32 + (row&31))*8 + (col&7);
      unsigned ov = OtInt[foff];
      float other = bf2f((u16)(ov>>16)) + bf2f((u16)(ov&0xffffu));
      v = sigmoidf_(v) * other;
      u16 hh = f2bf(v);
      u16 hl = f2bf(v - bf2f(hh));
      outHi[foff] = hh;
      outLo[foff] = hl;
    }
  }
}

// ============ final GEMM: dual split A pairs -> tanh f32 out =================
__global__ __launch_bounds__(256,1) void gemm_final(
    const u16* __restrict__ Ahi,  const u16* __restrict__ Alo,
    const u16* __restrict__ A2hi, const u16* __restrict__ A2lo,
    const u16* __restrict__ Whi,  const u16* __restrict__ Wlo,
    const u16* __restrict__ W2hi, const u16* __restrict__ W2lo,
    const float* __restrict__ bias,
    float* __restrict__ outF)
{
  int bx = blockIdx.x;
  int nt = bx & 7, mt = bx >> 3;
  int n0 = nt*64;
  int tid = threadIdx.x, lane = tid & 63, w = tid >> 6;
  size_t aBase = (size_t)mt*65536;

  f32x16 a0[2], a1[2], a2[2];
  #pragma unroll
  for (int c=0;c<2;c++){
    a0[c]=(f32x16)(0.f); a1[c]=(f32x16)(0.f); a2[c]=(f32x16)(0.f);
  }

  for (int pair=0; pair<2; ++pair){
    const u16* ah = pair ? A2hi : Ahi;
    const u16* al = pair ? A2lo : Alo;
    const u16* wh = pair ? W2hi : Whi;
    const u16* wl = pair ? W2lo : Wlo;
    #pragma unroll 2
    for (int kk=0; kk<32; ++kk){
      size_t aoff = aBase + (((size_t)kk*4 + w)*64 + lane)*8;
      s16x8 fah = *(const s16x8*)(ah + aoff);
      s16x8 fal = *(const s16x8*)(al + aoff);
      #pragma unroll
      for (int c=0;c<2;c++){
        size_t woff = (((size_t)kk*16 + nt*2 + c)*64 + lane)*8;
        s16x8 fwh = *(const s16x8*)(wh + woff);
        s16x8 fwl = *(const s16x8*)(wl + woff);
        a0[c] = __builtin_amdgcn_mfma_f32_32x32x16_bf16(fah, fwh, a0[c], 0,0,0);
        a1[c] = __builtin_amdgcn_mfma_f32_32x32x16_bf16(fah, fwl, a1[c], 0,0,0);
        a2[c] = __builtin_amdgcn_mfma_f32_32x32x16_bf16(fal, fwh, a2[c], 0,0,0);
      }
    }
  }

  #pragma unroll
  for (int c=0;c<2;c++){
    f32x16 acc = a0[c] + a1[c] + a2[c];
    int col = n0 + c*32 + (lane&31);
    float b = bias[col];
    #pragma unroll
    for (int r=0;r<16;r++){
      int row = w*32 + (r&3) + 8*(r>>2) + 4*(lane>>5);
      float v = tanhf(acc[r] + b);
      outF[((size_t)row*256 + mt)*512 + col] = v;
    }
  }
}

// ============ launch ==========================================================
extern "C" void kernel_launch(void* const* d_in, const int* in_sizes, int n_in,
                              void* d_out, int out_size, void* d_ws, size_t ws_size,
                              hipStream_t stream)
{
  const float* feat0  = (const float*)d_in[0];
  const float* feat1  = (const float*)d_in[1];
  const float* fmask  = (const float*)d_in[2];
  const float* w_emb0 = (const float*)d_in[3];
  const float* b_emb0 = (const float*)d_in[4];
  const float* gamma0 = (const float*)d_in[5];
  const float* beta0  = (const float*)d_in[6];
  const float* w_emb1 = (const float*)d_in[7];
  const float* b_emb1 = (const float*)d_in[8];
  const float* gamma1 = (const float*)d_in[9];
  const float* beta1  = (const float*)d_in[10];
  const float* w_ih0  = (const float*)d_in[11];
  const float* w_hh0  = (const float*)d_in[12];
  const float* b_ih0  = (const float*)d_in[13];
  const float* b_hh0  = (const float*)d_in[14];
  const float* w_ih1  = (const float*)d_in[15];
  const float* w_hh1  = (const float*)d_in[16];
  const float* b_ih1  = (const float*)d_in[17];
  const float* b_hh1  = (const float*)d_in[18];
  const float* wg0    = (const float*)d_in[19];
  const float* bg0    = (const float*)d_in[20];
  const float* wg1    = (const float*)d_in[21];
  const float* bg1    = (const float*)d_in[22];
  const float* wf1    = (const float*)d_in[23];
  const float* wf2    = (const float*)d_in[24];
  const float* bf     = (const float*)d_in[25];
  float* out = (float*)d_out;

  char* ws = (char*)d_ws;
  u16* e0hi = (u16*)(ws + 0);
  u16* e0lo = (u16*)(ws + 33554432);
  u16* e1hi = (u16*)(ws + 67108864);
  u16* e1lo = (u16*)(ws + 100663296);
  unsigned* H0int = (unsigned*)(ws + 134217728);
  unsigned* H1int = (unsigned*)(ws + 201588736);
  int*   barp  = (int*)(ws + 269484032);     // flags (pre-scan region)
  float* psum  = (float*)(ws + 269484032);
  float* psq   = (float*)(ws + 269746176);
  float* meanb = (float*)(ws + 270008320);
  float* scaleb= (float*)(ws + 270010368);
  float* bc0   = (float*)(ws + 270012416);
  float* bc1   = (float*)(ws + 270020608);
  u16* wr0hi = (u16*)(ws + 270028800);
  u16* wr0lo = (u16*)(ws + 274223104);
  u16* wr1hi = (u16*)(ws + 278417408);
  u16* wr1lo = (u16*)(ws + 282611712);
  u16* we0hi = (u16*)(ws + 286806016);
  u16* we0lo = (u16*)(ws + 288903168);
  u16* we1hi = (u16*)(ws + 291000320);
  u16* we1lo = (u16*)(ws + 292048896);
  u16* wg0hi = (u16*)(ws + 293097472);
  u16* wg0lo = (u16*)(ws + 293621760);
  u16* wg1hi = (u16*)(ws + 294146048);
  u16* wg1lo = (u16*)(ws + 294670336);
  u16* wf1hi = (u16*)(ws + 295194624);
  u16* wf1lo = (u16*)(ws + 295718912);
  u16* wf2hi = (u16*)(ws + 296243200);
  u16* wf2lo = (u16*)(ws + 296767488);
  float* Ytmp = (float*)(ws + 134217728);   // aliases H0int, pre-scan only

  // ---- weight prep ----
  split_gates2<<<dim3(2048), dim3(256), 0, stream>>>(w_ih0, w_hh0, b_ih0, b_hh0, wr0hi, wr0lo, bc0);
  split_gates2<<<dim3(2048), dim3(256), 0, stream>>>(w_ih1, w_hh1, b_ih1, b_hh1, wr1hi, wr1lo, bc1);
  split_plain<<<dim3(4096), dim3(256), 0, stream>>>(w_emb0, we0hi, we0lo, 1048576);
  split_plain<<<dim3(2048), dim3(256), 0, stream>>>(w_emb1, we1hi, we1lo, 524288);
  split_fragW<<<dim3(1024), dim3(256), 0, stream>>>(wg0, wg0hi, wg0lo, 512, 512);
  split_fragW<<<dim3(1024), dim3(256), 0, stream>>>(wg1, wg1hi, wg1lo, 512, 512);
  split_fragW<<<dim3(1024), dim3(256), 0, stream>>>(wf1, wf1hi, wf1lo, 512, 512);
  split_fragW<<<dim3(1024), dim3(256), 0, stream>>>(wf2, wf2hi, wf2lo, 512, 512);

  // ---- embeddings + BN (Y temp in H0int region) ----
  gemm_emb<<<dim3(1024), dim3(256), 0, stream>>>(feat0, we0hi, we0lo, b_emb0, Ytmp, 2048);
  bn_stats1<<<dim3(128), dim3(256), 0, stream>>>(Ytmp, psum, psq);
  bn_stats2<<<dim3(1),   dim3(512), 0, stream>>>(psum, psq, meanb, scaleb);
  bn_apply_split<<<dim3(8192), dim3(256), 0, stream>>>(Ytmp, meanb, scaleb, gamma0, beta0, e0hi, e0lo);

  gemm_emb<<<dim3(1024), dim3(256), 0, stream>>>(feat1, we1hi, we1lo, b_emb1, Ytmp, 1024);
  bn_stats1<<<dim3(128), dim3(256), 0, stream>>>(Ytmp, psum, psq);
  bn_stats2<<<dim3(1),   dim3(512), 0, stream>>>(psum, psq, meanb, scaleb);
  bn_apply_split<<<dim3(8192), dim3(256), 0, stream>>>(Ytmp, meanb, scaleb, gamma1, beta1, e1hi, e1lo);

  // ---- persistent scan: 4 domains; all-to-all flag wait ----
  zero_init<<<dim3(256), dim3(256), 0, stream>>>(barp, H0int, H1int);
  ScanArgs sa;
  sa.e0hi=e0hi; sa.e0lo=e0lo; sa.e1hi=e1hi; sa.e1lo=e1lo;
  sa.wr0hi=wr0hi; sa.wr0lo=wr0lo; sa.wr1hi=wr1hi; sa.wr1lo=wr1lo;
  sa.bc0=bc0; sa.bc1=bc1; sa.mask=fmask;
  sa.H0=H0int; sa.H1=H1int;
  sa.flags=barp;
  scan_all<<<dim3(256), dim3(256), 0, stream>>>(sa);

  // ---- gate0 = sigmoid(h1@wg0^T+bg0)*h0 -> g0 planes (e0 region) ----
  gemm_gate<<<dim3(2048), dim3(256), 0, stream>>>(
      H1int + 65536, wg0hi, wg0lo, bg0, H0int + 65536, e0hi, e0lo);
  // ---- gate1 = sigmoid(h0@wg1^T+bg1)*h1 -> g1 planes (e1 region) ----
  gemm_gate<<<dim3(2048), dim3(256), 0, stream>>>(
      H0int + 65536, wg1hi, wg1lo, bg1, H1int + 65536, e1hi, e1lo);
  // ---- out = tanh(g0@wf1^T + g1@wf2^T + bf) ----
  gemm_final<<<dim3(2048), dim3(256), 0, stream>>>(
      e0hi, e0lo, e1hi, e1lo,
      wf1hi, wf1lo, wf2hi, wf2lo, bf, out);
}

// Round 18
// 6863.325 us; speedup vs baseline: 1.3156x; 1.0974x over previous
//
#include <hip/hip_runtime.h>
#include <math.h>

// Dims: B=128, T=256, D=512, F0=2048, F1=1024, R=B*T=32768
//
// ws layout (BYTE offsets):
//  e0hi @ 0, e0lo @ 33554432, e1hi @ 67108864, e1lo @ 100663296
//  H0int @ 134217728 (67371008 B: 257 slots x 65536 u32, (hi<<16)|lo)
//  H1int @ 201588736 (67371008 B)
//  bar  @ 269484032  flags[4][64][16] ints (pre-scan region)
//  psum @ 269484032, psq @ 269746176, mean @ 270008320, scl @ 270010368
//  bc0 @ 270012416, bc1 @ 270020608
//  wr0hi@ 270028800, wr0lo@ 274223104, wr1hi@ 278417408, wr1lo@ 282611712
//  we0hi@ 286806016, we0lo@ 288903168, we1hi@ 291000320, we1lo@ 292048896
//  wg0hi@ 293097472 .. wf2lo@ 296767488
//  Y temp (fp32 64MB) aliases H0int (pre-scan only).
//
// r18 = EXACT r17 + ONE change: grouped slice-granular waits. Consumer kk
// slice needs only strips {2kk,2kk+1}; K-loop split into 4 groups of 8
// slices, each preceded by a 16-flag wait (strips [16g,16g+16)). The
// monolithic 64-flag wait is deleted -> producer publish latency overlaps
// with K-loop compute. Publish protocol unchanged.

typedef short s16x8 __attribute__((ext_vector_type(8)));
typedef float f32x4 __attribute__((ext_vector_type(4)));
typedef float f32x16 __attribute__((ext_vector_type(16)));
typedef unsigned short u16;

__device__ __forceinline__ float sigmoidf_(float x){ return 1.0f/(1.0f+expf(-x)); }

__device__ __forceinline__ u16 f2bf(float x){
  unsigned int u = __float_as_uint(x);
  unsigned int r = u + 0x7fffu + ((u>>16)&1u);
  return (u16)(r>>16);
}
__device__ __forceinline__ float bf2f(u16 s){ return __uint_as_float(((unsigned int)s)<<16); }

// unpack 8 interleaved u32 ((hi<<16)|lo) -> two s16x8 fragments
__device__ __forceinline__ void unpack8(const unsigned int* __restrict__ p,
                                        s16x8& hi, s16x8& lo){
  uint4 w0 = *(const uint4*)p;
  uint4 w1 = *(const uint4*)(p+4);
  union { unsigned int u[4]; s16x8 v; } H, L;
  H.u[0] = (w0.x>>16) | (w0.y & 0xffff0000u);
  H.u[1] = (w0.z>>16) | (w0.w & 0xffff0000u);
  H.u[2] = (w1.x>>16) | (w1.y & 0xffff0000u);
  H.u[3] = (w1.z>>16) | (w1.w & 0xffff0000u);
  L.u[0] = (w0.x & 0xffffu) | (w0.y<<16);
  L.u[1] = (w0.z & 0xffffu) | (w0.w<<16);
  L.u[2] = (w1.x & 0xffffu) | (w1.y<<16);
  L.u[3] = (w1.z & 0xffffu) | (w1.w<<16);
  hi = H.v; lo = L.v;
}

// ============ weight prep ====================================================
__global__ __launch_bounds__(256) void split_plain(const float* __restrict__ src,
                                                   u16* __restrict__ hi, u16* __restrict__ lo, int n)
{
  int i = blockIdx.x*256 + threadIdx.x;
  if (i < n){
    float v = src[i];
    u16 h = f2bf(v);
    hi[i] = h;
    lo[i] = f2bf(v - bf2f(h));
  }
}

__global__ __launch_bounds__(256) void split_fragW(const float* __restrict__ src,
                                                   u16* __restrict__ hi, u16* __restrict__ lo,
                                                   int N, int K)
{
  int i = blockIdx.x*256 + threadIdx.x;
  if (i >= N*K) return;
  int n = i / K, k = i - n*K;
  float v = src[i];
  u16 h = f2bf(v), l2 = f2bf(v - bf2f(h));
  size_t off = ((((size_t)(k>>4)*(N/32) + (n>>5))*64) + ((k>>3)&1)*32 + (n&31))*8 + (k&7);
  hi[off] = h; lo[off] = l2;
}

__global__ __launch_bounds__(256) void split_gates2(const float* __restrict__ wih,
                                                    const float* __restrict__ whh,
                                                    const float* __restrict__ bih,
                                                    const float* __restrict__ bhh,
                                                    u16* __restrict__ hi, u16* __restrict__ lo,
                                                    float* __restrict__ bc)
{
  int np = blockIdx.x;            // 0..2047
  int d = np>>2, q = np&3;
  int orow = q*512 + d;
  for (int k = threadIdx.x; k < 1024; k += 256){
    float v = (k < 512) ? wih[(size_t)orow*512 + k] : whh[(size_t)orow*512 + (k-512)];
    u16 h = f2bf(v), l2 = f2bf(v - bf2f(h));
    size_t off = (((size_t)(k>>4)*64 + (np>>5))*64 + ((k>>3)&1)*32 + (np&31))*8 + (k&7);
    hi[off] = h; lo[off] = l2;
  }
  if (threadIdx.x == 0) bc[np] = bih[orow] + bhh[orow];
}

// ============ emb GEMM (A fp32, in-kernel split) =============================
__global__ __launch_bounds__(256) void gemm_emb(
    const float* __restrict__ A, const u16* __restrict__ Whi, const u16* __restrict__ Wlo,
    const float* __restrict__ bias, float* __restrict__ out, int K)
{
  __shared__ u16 Ah[128][40];
  __shared__ u16 Al[128][40];
  __shared__ u16 Wh[128][40];
  __shared__ u16 Wl[128][40];

  int bx = blockIdx.x;
  int nt = bx & 3, mt = bx >> 2;
  int m0 = mt*128, n0 = nt*128;
  int tid = threadIdx.x, lane = tid & 63, w = tid >> 6;
  int wm = (w>>1)*64, wn = (w&1)*64;

  f32x4 acc[4][4];
  #pragma unroll
  for (int i=0;i<4;i++)
    #pragma unroll
    for (int j=0;j<4;j++) acc[i][j] = (f32x4){0.f,0.f,0.f,0.f};

  for (int k0=0; k0<K; k0+=32){
    #pragma unroll
    for (int p=0;p<4;p++){
      int fi = p*256 + tid;
      int r = fi>>3, c = fi&7;
      float4 v = *(const float4*)&A[(size_t)(m0+r)*K + k0 + c*4];
      u16 h0=f2bf(v.x), h1=f2bf(v.y), h2=f2bf(v.z), h3=f2bf(v.w);
      u16 l0=f2bf(v.x-bf2f(h0)), l1=f2bf(v.y-bf2f(h1)), l2=f2bf(v.z-bf2f(h2)), l3=f2bf(v.w-bf2f(h3));
      uint2 ph = { (unsigned)h0 | ((unsigned)h1<<16), (unsigned)h2 | ((unsigned)h3<<16) };
      uint2 pl = { (unsigned)l0 | ((unsigned)l1<<16), (unsigned)l2 | ((unsigned)l3<<16) };
      *(uint2*)&Ah[r][c*4] = ph;
      *(uint2*)&Al[r][c*4] = pl;
    }
    #pragma unroll
    for (int p=0;p<2;p++){
      int fi = p*256 + tid;
      int r = fi>>2, c = fi&3;
      uint4 vh = *(const uint4*)&Whi[(size_t)(n0+r)*K + k0 + c*8];
      uint4 vl = *(const uint4*)&Wlo[(size_t)(n0+r)*K + k0 + c*8];
      *(uint4*)&Wh[r][c*8] = vh;
      *(uint4*)&Wl[r][c*8] = vl;
    }
    __syncthreads();
    s16x8 ah[4], al[4];
    #pragma unroll
    for (int mf=0;mf<4;mf++){
      ah[mf] = *(const s16x8*)&Ah[wm + mf*16 + (lane&15)][(lane>>4)*8];
      al[mf] = *(const s16x8*)&Al[wm + mf*16 + (lane&15)][(lane>>4)*8];
    }
    #pragma unroll
    for (int nf=0;nf<4;nf++){
      s16x8 wh = *(const s16x8*)&Wh[wn + nf*16 + (lane&15)][(lane>>4)*8];
      s16x8 wl = *(const s16x8*)&Wl[wn + nf*16 + (lane&15)][(lane>>4)*8];
      #pragma unroll
      for (int mf=0;mf<4;mf++){
        acc[mf][nf] = __builtin_amdgcn_mfma_f32_16x16x32_bf16(ah[mf], wh, acc[mf][nf], 0,0,0);
        acc[mf][nf] = __builtin_amdgcn_mfma_f32_16x16x32_bf16(ah[mf], wl, acc[mf][nf], 0,0,0);
        acc[mf][nf] = __builtin_amdgcn_mfma_f32_16x16x32_bf16(al[mf], wh, acc[mf][nf], 0,0,0);
      }
    }
    __syncthreads();
  }
  #pragma unroll
  for (int mf=0;mf<4;mf++){
    #pragma unroll
    for (int nf=0;nf<4;nf++){
      int col = n0 + wn + nf*16 + (lane&15);
      int row0 = m0 + wm + mf*16 + (lane>>4)*4;
      float b = bias[col];
      #pragma unroll
      for (int g=0; g<4; ++g){
        out[(size_t)(row0+g)*512 + col] = acc[mf][nf][g] + b;
      }
    }
  }
}

// ============ BN ==============================================================
__global__ __launch_bounds__(256) void bn_stats1(const float* __restrict__ Y,
                                                 float* __restrict__ psum,
                                                 float* __restrict__ psq)
{
  int blk = blockIdx.x;
  int tid = threadIdx.x;
  const float* base = Y + (size_t)blk*256*512;
  float sx=0.f, sy=0.f, qx=0.f, qy=0.f;
  for (int r=0;r<256;r++){
    float2 v = *(const float2*)&base[(size_t)r*512 + tid*2];
    sx += v.x; sy += v.y; qx += v.x*v.x; qy += v.y*v.y;
  }
  psum[(size_t)blk*512 + tid*2]   = sx;
  psum[(size_t)blk*512 + tid*2+1] = sy;
  psq [(size_t)blk*512 + tid*2]   = qx;
  psq [(size_t)blk*512 + tid*2+1] = qy;
}

__global__ __launch_bounds__(512) void bn_stats2(const float* __restrict__ psum,
                                                 const float* __restrict__ psq,
                                                 float* __restrict__ mean,
                                                 float* __restrict__ scale)
{
  int c = threadIdx.x;
  float s=0.f, q=0.f;
  for (int b=0;b<128;b++){ s += psum[(size_t)b*512+c]; q += psq[(size_t)b*512+c]; }
  float mu = s * (1.0f/32768.0f);
  float var = q * (1.0f/32768.0f) - mu*mu;
  mean[c] = mu;
  scale[c] = rsqrtf(var + 1e-5f);
}

// BN+ReLU, split to hi/lo, write frag-layout e planes (row r=b*256+t -> slot t, row b)
__global__ __launch_bounds__(256) void bn_apply_split(const float* __restrict__ Y,
                                                      const float* __restrict__ mean,
                                                      const float* __restrict__ scale,
                                                      const float* __restrict__ gamma,
                                                      const float* __restrict__ beta,
                                                      u16* __restrict__ ehi, u16* __restrict__ elo)
{
  size_t idx = (size_t)blockIdx.x*256 + threadIdx.x;  // 32768*64
  int r = (int)(idx >> 6);
  int c0 = (int)(idx & 63) * 8;
  int b = r >> 8, t = r & 255;
  float4 v0 = *(const float4*)&Y[(size_t)r*512 + c0];
  float4 v1 = *(const float4*)&Y[(size_t)r*512 + c0 + 4];
  float vv[8] = {v0.x,v0.y,v0.z,v0.w,v1.x,v1.y,v1.z,v1.w};
  unsigned int hw[4], lw[4];
  #pragma unroll
  for (int u=0;u<8;u+=2){
    float xa = fmaxf((vv[u]  -mean[c0+u])  *scale[c0+u]  *gamma[c0+u]  +beta[c0+u],   0.f);
    float xb = fmaxf((vv[u+1]-mean[c0+u+1])*scale[c0+u+1]*gamma[c0+u+1]+beta[c0+u+1], 0.f);
    u16 ha = f2bf(xa), hb = f2bf(xb);
    u16 la = f2bf(xa - bf2f(ha)), lb = f2bf(xb - bf2f(hb));
    hw[u>>1] = (unsigned)ha | ((unsigned)hb<<16);
    lw[u>>1] = (unsigned)la | ((unsigned)lb<<16);
  }
  size_t off = (size_t)t*65536 + ((((size_t)(c0>>4)*4 + (b>>5))*64) + ((c0>>3)&1)*32 + (b&31))*8;
  uint4 ph = {hw[0],hw[1],hw[2],hw[3]};
  uint4 pl = {lw[0],lw[1],lw[2],lw[3]};
  *(uint4*)&ehi[off] = ph;
  *(uint4*)&elo[off] = pl;
}

// ============ barrier + H-slot0 init =========================================
__global__ __launch_bounds__(256) void zero_init(int* __restrict__ bar,
                                                 unsigned* __restrict__ H0,
                                                 unsigned* __restrict__ H1)
{
  int i = blockIdx.x*256 + threadIdx.x;   // 256 blocks -> 65536 threads
  if (i < 4096) bar[i] = 0;               // flags[4][64][16]
  H0[i] = 0u;
  H1[i] = 0u;
}

// ============ persistent scan: r17 + grouped slice-granular waits ============
// 256 blocks = cell(2) x strip(64 of 32 permuted cols) x rowhalf(2 of 64 rows).
// Barrier domain = (cell,rowhalf): 4 independent groups of 64 blocks.
// Consumer K-loop split into 4 groups of 8 kk-slices; group g waits only on
// the 16 producer flags of strips [16g,16g+16) (kk slice covers d in
// [16kk,16kk+16) = strips 2kk,2kk+1). No monolithic wait.
// Publish: epilogue-interleaved atomicExch; tid==128 flags after sig==2(t+1).
struct ScanArgs {
  const u16 *e0hi, *e0lo, *e1hi, *e1lo;
  const u16 *wr0hi, *wr0lo, *wr1hi, *wr1lo;
  const float *bc0, *bc1, *mask;
  unsigned *H0, *H1;
  int *flags;   // [4][64][16]
};

__global__ __launch_bounds__(256) void scan_all(ScanArgs A)
{
  __shared__ u16 Wlds[64][64][8];        // 64 KB: W-hi [ksub][lane][8]
  __shared__ float red[2][2][16][65];    // 16.6 KB [phase][pair][elem][lane]
  __shared__ int sig;                    // monotonic, +2 per step

  int bx = blockIdx.x;
  int ci = bx>>7, s = (bx>>1)&63, rh = bx&1;
  int dom = ci*2 + rh;                   // barrier domain (cell,rowhalf)
  int cb = s;                            // block index within domain (0..63)
  int tid = threadIdx.x, lane = tid&63, w = tid>>6;
  int khalf = w>>1, pr = w&1;
  int rt = rh*2 + pr;

  int* flags = A.flags + dom*64*16;

  const u16* ehi = ci? A.e1hi : A.e0hi;
  const u16* elo = ci? A.e1lo : A.e0lo;
  const u16* whi = ci? A.wr1hi : A.wr0hi;
  const u16* wlo = ci? A.wr1lo : A.wr0lo;
  const float* bc = ci? A.bc1 : A.bc0;
  unsigned* Hc = ci? A.H1 : A.H0;

  if (tid == 0) sig = 0;

  // stage W-hi strip into LDS (once): [ks][ct=s][lane][8]
  for (int it=0; it<16; ++it){
    int cid = it*256 + tid;
    int ks = cid>>6, l8 = cid&63;
    const u16* src = whi + (((size_t)ks*64 + s)*64 + l8)*8;
    *(uint4*)&Wlds[ks][l8][0] = *(const uint4*)src;
  }
  __syncthreads();

  int q = lane&3;
  int np = s*32 + (lane&31);
  int d  = np>>2;
  float bcv = bc[np];
  float creg[4] = {0.f,0.f,0.f,0.f};    // c-state (H-waves)

  for (int t=0; t<256; ++t){
    size_t abase = (size_t)t*65536;

    if (khalf == 0){
      // ---- e-waves: no wait, compute and hand off partials ----
      f32x16 a0=(f32x16)(0.f), a1=(f32x16)(0.f), a2=(f32x16)(0.f);
      #pragma unroll 4
      for (int kk=0; kk<32; ++kk){
        size_t aoff = abase + ((size_t)(kk*4 + rt)*64 + lane)*8;
        s16x8 fah = *(const s16x8*)(ehi + aoff);
        s16x8 fal = *(const s16x8*)(elo + aoff);
        s16x8 fwh = *(const s16x8*)&Wlds[kk][lane][0];
        s16x8 fwl = *(const s16x8*)(wlo + (((size_t)kk*64 + s)*64 + lane)*8);
        a0 = __builtin_amdgcn_mfma_f32_32x32x16_bf16(fah, fwh, a0, 0,0,0);
        a1 = __builtin_amdgcn_mfma_f32_32x32x16_bf16(fah, fwl, a1, 0,0,0);
        a2 = __builtin_amdgcn_mfma_f32_32x32x16_bf16(fal, fwh, a2, 0,0,0);
      }
      f32x16 t3 = a0 + a1 + a2;
      #pragma unroll
      for (int e=0;e<16;e++) red[t&1][pr][e][lane] = t3[e];
      __syncthreads();
    } else {
      // ---- H-waves: grouped slice waits pipelined with K-loop ----
      f32x16 a0=(f32x16)(0.f), a1=(f32x16)(0.f), a2=(f32x16)(0.f);
      #pragma unroll
      for (int g=0; g<4; ++g){
        // wait only for the 16 producers of slices kk in [8g, 8g+8)
        {
          int v;
          do {
            v = __hip_atomic_load(&flags[(g*16 + (lane&15))*16], __ATOMIC_RELAXED, __HIP_MEMORY_SCOPE_AGENT);
            if (v < t) __builtin_amdgcn_s_sleep(1);
          } while (v < t);
        }
        asm volatile("" ::: "memory");   // no load hoisting above the wait
        #pragma unroll 8
        for (int kk=g*8; kk<g*8+8; ++kk){
          size_t aoff = abase + ((size_t)(kk*4 + rt)*64 + lane)*8;
          s16x8 fah, fal;
          unpack8(Hc + aoff, fah, fal);
          int ks = 32 + kk;
          s16x8 fwh = *(const s16x8*)&Wlds[ks][lane][0];
          s16x8 fwl = *(const s16x8*)(wlo + (((size_t)ks*64 + s)*64 + lane)*8);
          a0 = __builtin_amdgcn_mfma_f32_32x32x16_bf16(fah, fwh, a0, 0,0,0);
          a1 = __builtin_amdgcn_mfma_f32_32x32x16_bf16(fah, fwl, a1, 0,0,0);
          a2 = __builtin_amdgcn_mfma_f32_32x32x16_bf16(fal, fwh, a2, 0,0,0);
        }
      }
      f32x16 mine = a0 + a1 + a2;
      __syncthreads();                 // e-partials of step t ready in red[t&1]

      f32x16 tot;
      #pragma unroll
      for (int e=0;e<16;e++) tot[e] = mine[e] + red[t&1][pr][e][lane];

      size_t hSlot = (size_t)(t+1)*65536;
      #pragma unroll
      for (int r=0;r<16;r++){
        float pre = tot[r] + bcv;
        float act = (q==2) ? tanhf(pre) : sigmoidf_(pre);
        float v1 = __shfl_xor(act, 1);
        float v2 = __shfl_xor(act, 2);
        float v3 = __shfl_xor(v1, 2);
        float gi = (q==0)? act : (q==1)? v1 : (q==2)? v2 : v3;
        float gf = (q==1)? act : (q==0)? v1 : (q==3)? v2 : v3;
        float gg = (q==2)? act : (q==3)? v1 : (q==0)? v2 : v3;
        float go = (q==3)? act : (q==2)? v1 : (q==1)? v2 : v3;
        if (q == (r&3)){
          int ri = r>>2;
          int row = rh*64 + pr*32 + (r&3) + 8*ri + 4*(lane>>5);
          float cold = creg[ri];
          float cn = gf*cold + gi*gg;
          float h  = go*tanhf(cn);
          float mv = A.mask[(size_t)row*256 + t];
          cn *= mv; h *= mv;
          creg[ri] = cn;
          u16 hh = f2bf(h), hl = f2bf(h - bf2f(hh));
          size_t hoff = hSlot + ((((size_t)(d>>4)*4 + (row>>5))*64) + ((d>>3)&1)*32 + (row&31))*8 + (d&7);
          atomicExch(&Hc[hoff], ((unsigned)hh<<16) | (unsigned)hl);   // LLC-resident
        }
      }
      asm volatile("s_waitcnt vmcnt(0)" ::: "memory");  // atomics executed at LLC
      if (lane == 0) atomicAdd(&sig, 1);
      if (tid == 128){
        while (__hip_atomic_load(&sig, __ATOMIC_RELAXED, __HIP_MEMORY_SCOPE_WORKGROUP) < 2*(t+1))
          __builtin_amdgcn_s_sleep(1);
        atomicExch(&flags[cb*16], t+1);
      }
    }
  }
}

// ============ gate GEMM: A,Other = interleaved H; out = split g planes =======
__global__ __launch_bounds__(256,1) void gemm_gate(
    const unsigned* __restrict__ Aint,
    const u16* __restrict__ Whi,  const u16* __restrict__ Wlo,
    const float* __restrict__ bias,
    const unsigned* __restrict__ OtInt,
    u16* __restrict__ outHi, u16* __restrict__ outLo)
{
  int bx = blockIdx.x;
  int nt = bx & 7, mt = bx >> 3;
  int n0 = nt*64;
  int tid = threadIdx.x, lane = tid & 63, w = tid >> 6;
  size_t aBase = (size_t)mt*65536;

  f32x16 a0[2], a1[2], a2[2];
  #pragma unroll
  for (int c=0;c<2;c++){
    a0[c]=(f32x16)(0.f); a1[c]=(f32x16)(0.f); a2[c]=(f32x16)(0.f);
  }

  #pragma unroll 2
  for (int kk=0; kk<32; ++kk){
    size_t aoff = aBase + (((size_t)kk*4 + w)*64 + lane)*8;
    s16x8 fah, fal;
    unpack8(Aint + aoff, fah, fal);
    #pragma unroll
    for (int c=0;c<2;c++){
      size_t woff = (((size_t)kk*16 + nt*2 + c)*64 + lane)*8;
      s16x8 fwh = *(const s16x8*)(Whi + woff);
      s16x8 fwl = *(const s16x8*)(Wlo + woff);
      a0[c] = __builtin_amdgcn_mfma_f32_32x32x16_bf16(fah, fwh, a0[c], 0,0,0);
      a1[c] = __builtin_amdgcn_mfma_f32_32x32x16_bf16(fah, fwl, a1[c], 0,0,0);
      a2[c] = __builtin_amdgcn_mfma_f32_32x32x16_bf16(fal, fwh, a2[c], 0,0,0);
    }
  }

  #pragma unroll
  for (int c=0;c<2;c++){
    f32x16 acc = a0[c] + a1[c] + a2[c];
    int col = n0 + c*32 + (lane&31);
    float b = bias[col];
    #pragma unroll
    for (int r=0;r<16;r++){
      int row = w*32 + (r&3) + 8*(r>>2) + 4*(lane>>5);
      float v = acc[r] + b;
      size_t foff = aBase + ((((size_t)(col>>4)*4 + w)*64) + ((col>>3)&1)*32 + (row&31))*8 + (col&7);
      unsigned ov = OtInt[foff];
      float other = bf2f((u16)(ov>>16)) + bf2f((u16)(ov&0xffffu));
      v = sigmoidf_(v) * other;
      u16 hh = f2bf(v);
      u16 hl = f2bf(v - bf2f(hh));
      outHi[foff] = hh;
      outLo[foff] = hl;
    }
  }
}

// ============ final GEMM: dual split A pairs -> tanh f32 out =================
__global__ __launch_bounds__(256,1) void gemm_final(
    const u16* __restrict__ Ahi,  const u16* __restrict__ Alo,
    const u16* __restrict__ A2hi, const u16* __restrict__ A2lo,
    const u16* __restrict__ Whi,  const u16* __restrict__ Wlo,
    const u16* __restrict__ W2hi, const u16* __restrict__ W2lo,
    const float* __restrict__ bias,
    float* __restrict__ outF)
{
  int bx = blockIdx.x;
  int nt = bx & 7, mt = bx >> 3;
  int n0 = nt*64;
  int tid = threadIdx.x, lane = tid & 63, w = tid >> 6;
  size_t aBase = (size_t)mt*65536;

  f32x16 a0[2], a1[2], a2[2];
  #pragma unroll
  for (int c=0;c<2;c++){
    a0[c]=(f32x16)(0.f); a1[c]=(f32x16)(0.f); a2[c]=(f32x16)(0.f);
  }

  for (int pair=0; pair<2; ++pair){
    const u16* ah = pair ? A2hi : Ahi;
    const u16* al = pair ? A2lo : Alo;
    const u16* wh = pair ? W2hi : Whi;
    const u16* wl = pair ? W2lo : Wlo;
    #pragma unroll 2
    for (int kk=0; kk<32; ++kk){
      size_t aoff = aBase + (((size_t)kk*4 + w)*64 + lane)*8;
      s16x8 fah = *(const s16x8*)(ah + aoff);
      s16x8 fal = *(const s16x8*)(al + aoff);
      #pragma unroll
      for (int c=0;c<2;c++){
        size_t woff = (((size_t)kk*16 + nt*2 + c)*64 + lane)*8;
        s16x8 fwh = *(const s16x8*)(wh + woff);
        s16x8 fwl = *(const s16x8*)(wl + woff);
        a0[c] = __builtin_amdgcn_mfma_f32_32x32x16_bf16(fah, fwh, a0[c], 0,0,0);
        a1[c] = __builtin_amdgcn_mfma_f32_32x32x16_bf16(fah, fwl, a1[c], 0,0,0);
        a2[c] = __builtin_amdgcn_mfma_f32_32x32x16_bf16(fal, fwh, a2[c], 0,0,0);
      }
    }
  }

  #pragma unroll
  for (int c=0;c<2;c++){
    f32x16 acc = a0[c] + a1[c] + a2[c];
    int col = n0 + c*32 + (lane&31);
    float b = bias[col];
    #pragma unroll
    for (int r=0;r<16;r++){
      int row = w*32 + (r&3) + 8*(r>>2) + 4*(lane>>5);
      float v = tanhf(acc[r] + b);
      outF[((size_t)row*256 + mt)*512 + col] = v;
    }
  }
}

// ============ launch ==========================================================
extern "C" void kernel_launch(void* const* d_in, const int* in_sizes, int n_in,
                              void* d_out, int out_size, void* d_ws, size_t ws_size,
                              hipStream_t stream)
{
  const float* feat0  = (const float*)d_in[0];
  const float* feat1  = (const float*)d_in[1];
  const float* fmask  = (const float*)d_in[2];
  const float* w_emb0 = (const float*)d_in[3];
  const float* b_emb0 = (const float*)d_in[4];
  const float* gamma0 = (const float*)d_in[5];
  const float* beta0  = (const float*)d_in[6];
  const float* w_emb1 = (const float*)d_in[7];
  const float* b_emb1 = (const float*)d_in[8];
  const float* gamma1 = (const float*)d_in[9];
  const float* beta1  = (const float*)d_in[10];
  const float* w_ih0  = (const float*)d_in[11];
  const float* w_hh0  = (const float*)d_in[12];
  const float* b_ih0  = (const float*)d_in[13];
  const float* b_hh0  = (const float*)d_in[14];
  const float* w_ih1  = (const float*)d_in[15];
  const float* w_hh1  = (const float*)d_in[16];
  const float* b_ih1  = (const float*)d_in[17];
  const float* b_hh1  = (const float*)d_in[18];
  const float* wg0    = (const float*)d_in[19];
  const float* bg0    = (const float*)d_in[20];
  const float* wg1    = (const float*)d_in[21];
  const float* bg1    = (const float*)d_in[22];
  const float* wf1    = (const float*)d_in[23];
  const float* wf2    = (const float*)d_in[24];
  const float* bf     = (const float*)d_in[25];
  float* out = (float*)d_out;

  char* ws = (char*)d_ws;
  u16* e0hi = (u16*)(ws + 0);
  u16* e0lo = (u16*)(ws + 33554432);
  u16* e1hi = (u16*)(ws + 67108864);
  u16* e1lo = (u16*)(ws + 100663296);
  unsigned* H0int = (unsigned*)(ws + 134217728);
  unsigned* H1int = (unsigned*)(ws + 201588736);
  int*   barp  = (int*)(ws + 269484032);     // flags (pre-scan region)
  float* psum  = (float*)(ws + 269484032);
  float* psq   = (float*)(ws + 269746176);
  float* meanb = (float*)(ws + 270008320);
  float* scaleb= (float*)(ws + 270010368);
  float* bc0   = (float*)(ws + 270012416);
  float* bc1   = (float*)(ws + 270020608);
  u16* wr0hi = (u16*)(ws + 270028800);
  u16* wr0lo = (u16*)(ws + 274223104);
  u16* wr1hi = (u16*)(ws + 278417408);
  u16* wr1lo = (u16*)(ws + 282611712);
  u16* we0hi = (u16*)(ws + 286806016);
  u16* we0lo = (u16*)(ws + 288903168);
  u16* we1hi = (u16*)(ws + 291000320);
  u16* we1lo = (u16*)(ws + 292048896);
  u16* wg0hi = (u16*)(ws + 293097472);
  u16* wg0lo = (u16*)(ws + 293621760);
  u16* wg1hi = (u16*)(ws + 294146048);
  u16* wg1lo = (u16*)(ws + 294670336);
  u16* wf1hi = (u16*)(ws + 295194624);
  u16* wf1lo = (u16*)(ws + 295718912);
  u16* wf2hi = (u16*)(ws + 296243200);
  u16* wf2lo = (u16*)(ws + 296767488);
  float* Ytmp = (float*)(ws + 134217728);   // aliases H0int, pre-scan only

  // ---- weight prep ----
  split_gates2<<<dim3(2048), dim3(256), 0, stream>>>(w_ih0, w_hh0, b_ih0, b_hh0, wr0hi, wr0lo, bc0);
  split_gates2<<<dim3(2048), dim3(256), 0, stream>>>(w_ih1, w_hh1, b_ih1, b_hh1, wr1hi, wr1lo, bc1);
  split_plain<<<dim3(4096), dim3(256), 0, stream>>>(w_emb0, we0hi, we0lo, 1048576);
  split_plain<<<dim3(2048), dim3(256), 0, stream>>>(w_emb1, we1hi, we1lo, 524288);
  split_fragW<<<dim3(1024), dim3(256), 0, stream>>>(wg0, wg0hi, wg0lo, 512, 512);
  split_fragW<<<dim3(1024), dim3(256), 0, stream>>>(wg1, wg1hi, wg1lo, 512, 512);
  split_fragW<<<dim3(1024), dim3(256), 0, stream>>>(wf1, wf1hi, wf1lo, 512, 512);
  split_fragW<<<dim3(1024), dim3(256), 0, stream>>>(wf2, wf2hi, wf2lo, 512, 512);

  // ---- embeddings + BN (Y temp in H0int region) ----
  gemm_emb<<<dim3(1024), dim3(256), 0, stream>>>(feat0, we0hi, we0lo, b_emb0, Ytmp, 2048);
  bn_stats1<<<dim3(128), dim3(256), 0, stream>>>(Ytmp, psum, psq);
  bn_stats2<<<dim3(1),   dim3(512), 0, stream>>>(psum, psq, meanb, scaleb);
  bn_apply_split<<<dim3(8192), dim3(256), 0, stream>>>(Ytmp, meanb, scaleb, gamma0, beta0, e0hi, e0lo);

  gemm_emb<<<dim3(1024), dim3(256), 0, stream>>>(feat1, we1hi, we1lo, b_emb1, Ytmp, 1024);
  bn_stats1<<<dim3(128), dim3(256), 0, stream>>>(Ytmp, psum, psq);
  bn_stats2<<<dim3(1),   dim3(512), 0, stream>>>(psum, psq, meanb, scaleb);
  bn_apply_split<<<dim3(8192), dim3(256), 0, stream>>>(Ytmp, meanb, scaleb, gamma1, beta1, e1hi, e1lo);

  // ---- persistent scan: 4 domains; grouped slice-granular waits ----
  zero_init<<<dim3(256), dim3(256), 0, stream>>>(barp, H0int, H1int);
  ScanArgs sa;
  sa.e0hi=e0hi; sa.e0lo=e0lo; sa.e1hi=e1hi; sa.e1lo=e1lo;
  sa.wr0hi=wr0hi; sa.wr0lo=wr0lo; sa.wr1hi=wr1hi; sa.wr1lo=wr1lo;
  sa.bc0=bc0; sa.bc1=bc1; sa.mask=fmask;
  sa.H0=H0int; sa.H1=H1int;
  sa.flags=barp;
  scan_all<<<dim3(256), dim3(256), 0, stream>>>(sa);

  // ---- gate0 = sigmoid(h1@wg0^T+bg0)*h0 -> g0 planes (e0 region) ----
  gemm_gate<<<dim3(2048), dim3(256), 0, stream>>>(
      H1int + 65536, wg0hi, wg0lo, bg0, H0int + 65536, e0hi, e0lo);
  // ---- gate1 = sigmoid(h0@wg1^T+bg1)*h1 -> g1 planes (e1 region) ----
  gemm_gate<<<dim3(2048), dim3(256), 0, stream>>>(
      H0int + 65536, wg1hi, wg1lo, bg1, H1int + 65536, e1hi, e1lo);
  // ---- out = tanh(g0@wf1^T + g1@wf2^T + bf) ----
  gemm_final<<<dim3(2048), dim3(256), 0, stream>>>(
      e0hi, e0lo, e1hi, e1lo,
      wf1hi, wf1lo, wf2hi, wf2lo, bf, out);
}